// Round 13
// baseline (1305.426 us; speedup 1.0000x reference)
//
#include <hip/hip_runtime.h>

#define T_SEQ   1024
#define E_DIM   1024
#define H_HEADS 16
#define D_HEAD  64
#define L_LAYERS 6
#define B_BATCH 2
#define F_DIM   4096
#define V_VOCAB 32000

typedef float f32x4 __attribute__((ext_vector_type(4)));
typedef short short8 __attribute__((ext_vector_type(8)));

__device__ __forceinline__ unsigned short f2bf(float f) {
  union { float f; unsigned int u; } v; v.f = f;
  unsigned int r = v.u + 0x7fffu + ((v.u >> 16) & 1u);  // RNE
  return (unsigned short)(r >> 16);
}

// async global->LDS, 16B per lane; lds dest = wave-uniform base + lane*16
#define GLDS16(gp, lp) __builtin_amdgcn_global_load_lds( \
    (const __attribute__((address_space(1))) void*)(gp), \
    (__attribute__((address_space(3))) void*)(lp), 16, 0, 0)

// ---------------- embedding: x = tok_w[idx] + pos_w ----------------
__global__ void embed_kernel(const int* __restrict__ idx, const float* __restrict__ tok,
                             const float* __restrict__ pos, float* __restrict__ x) {
  int i = blockIdx.x * 256 + threadIdx.x;
  int bt = i >> 8;
  int e4 = i & 255;
  int t  = bt & (T_SEQ - 1);
  int tokid = idx[bt];
  f32x4 a = *(const f32x4*)(tok + (size_t)tokid * E_DIM + e4 * 4);
  f32x4 p = *(const f32x4*)(pos + (size_t)t * E_DIM + e4 * 4);
  *(f32x4*)(x + (size_t)bt * E_DIM + e4 * 4) = a + p;
}

// ---------------- layernorm body (f32 in, bf16 out), 256 threads ----------------
__device__ __forceinline__ void ln_body(const float* __restrict__ x,
    const float* __restrict__ g, const float* __restrict__ b,
    unsigned short* __restrict__ out, int row) {
  int tid = threadIdx.x;
  const float* xr = x + (size_t)row * E_DIM;
  f32x4 v = *(const f32x4*)(xr + tid * 4);
  float s  = v[0] + v[1] + v[2] + v[3];
  float s2 = v[0]*v[0] + v[1]*v[1] + v[2]*v[2] + v[3]*v[3];
  #pragma unroll
  for (int off = 32; off > 0; off >>= 1) {
    s  += __shfl_xor(s,  off);
    s2 += __shfl_xor(s2, off);
  }
  __shared__ float red[2][4];
  int wave = tid >> 6;
  if ((tid & 63) == 0) { red[0][wave] = s; red[1][wave] = s2; }
  __syncthreads();
  s  = red[0][0] + red[0][1] + red[0][2] + red[0][3];
  s2 = red[1][0] + red[1][1] + red[1][2] + red[1][3];
  float mean = s * (1.0f / E_DIM);
  float var  = s2 * (1.0f / E_DIM) - mean * mean;
  float rstd = rsqrtf(var + 1e-5f);
  f32x4 gv = *(const f32x4*)(g + tid * 4);
  f32x4 bv = *(const f32x4*)(b + tid * 4);
  ushort4 o;
  o.x = f2bf((v[0] - mean) * rstd * gv[0] + bv[0]);
  o.y = f2bf((v[1] - mean) * rstd * gv[1] + bv[1]);
  o.z = f2bf((v[2] - mean) * rstd * gv[2] + bv[2]);
  o.w = f2bf((v[3] - mean) * rstd * gv[3] + bv[3]);
  *(ushort4*)(out + (size_t)row * E_DIM + tid * 4) = o;
}

__global__ void ln_kernel(const float* __restrict__ x, const float* __restrict__ g,
                          const float* __restrict__ b, unsigned short* __restrict__ out) {
  ln_body(x, g, b, out, blockIdx.x);
}

// ---------------- weight transpose+convert: W f32 [K][N] -> Wt bf16 [N][K] ----------------
__device__ __forceinline__ void wtrans_body(const float* __restrict__ W,
    unsigned short* __restrict__ Wt, int K, int N, int bx, int by) {
  __shared__ float tile[64][65];
  const int n0 = bx * 64, k0 = by * 64;
  const int tr  = threadIdx.x >> 4;
  const int tc4 = (threadIdx.x & 15) * 4;
  #pragma unroll
  for (int p = 0; p < 4; ++p) {
    f32x4 v = *(const f32x4*)(W + (size_t)(k0 + p * 16 + tr) * N + n0 + tc4);
    tile[p * 16 + tr][tc4 + 0] = v[0];
    tile[p * 16 + tr][tc4 + 1] = v[1];
    tile[p * 16 + tr][tc4 + 2] = v[2];
    tile[p * 16 + tr][tc4 + 3] = v[3];
  }
  __syncthreads();
  #pragma unroll
  for (int p = 0; p < 4; ++p) {
    int n = p * 16 + tr;
    ushort4 o;
    o.x = f2bf(tile[tc4 + 0][n]);
    o.y = f2bf(tile[tc4 + 1][n]);
    o.z = f2bf(tile[tc4 + 2][n]);
    o.w = f2bf(tile[tc4 + 3][n]);
    *(ushort4*)(Wt + (size_t)(n0 + n) * K + k0 + tc4) = o;
  }
}

// layer weights (q,k,v,p,w1,w2) + ln1 in one launch; grid = 3072 + 2048
__global__ __launch_bounds__(256) void wtrans6ln_kernel(const float* __restrict__ wq,
    const float* __restrict__ wk, const float* __restrict__ wv, const float* __restrict__ wp,
    const float* __restrict__ w1, const float* __restrict__ w2,
    const float* __restrict__ lng, const float* __restrict__ lnb,
    const float* __restrict__ x, unsigned short* __restrict__ wtb,
    unsigned short* __restrict__ hb) {
  const size_t EE = (size_t)E_DIM * E_DIM;
  const size_t EF = (size_t)E_DIM * F_DIM;
  const int id = blockIdx.x;
  if (id < 1024) {
    const int z = id >> 8, r = id & 255;
    const float* W = z == 0 ? wq : (z == 1 ? wk : (z == 2 ? wv : wp));
    wtrans_body(W, wtb + z * EE, E_DIM, E_DIM, r & 15, r >> 4);
  } else if (id < 2048) {
    const int r = id - 1024;
    wtrans_body(w1, wtb + 4 * EE, E_DIM, F_DIM, r & 63, r >> 6);
  } else if (id < 3072) {
    const int r = id - 2048;
    wtrans_body(w2, wtb + 4 * EE + EF, F_DIM, E_DIM, r & 15, r >> 4);
  } else {
    ln_body(x, lng, lnb, hb, id - 3072);
  }
}

// LM weight transpose + final layernorm; grid = 8000 + 2048
__global__ __launch_bounds__(256) void wtransv_ln_kernel(const float* __restrict__ wlm,
    const float* __restrict__ lng, const float* __restrict__ lnb,
    const float* __restrict__ x, unsigned short* __restrict__ wtb,
    unsigned short* __restrict__ hb) {
  const int id = blockIdx.x;
  if (id < 8000) wtrans_body(wlm, wtb, E_DIM, V_VOCAB, id % 500, id / 500);
  else           ln_body(x, lng, lnb, hb, id - 8000);
}

// ---------------- MFMA flash attention, split-key, all-waves-busy ----------------
__global__ __launch_bounds__(512) void attn_mfma_kernel(
    const unsigned short* __restrict__ qk, const unsigned short* __restrict__ vt,
    unsigned short* __restrict__ y) {
  __shared__ __align__(16) char smem[2 * 16384 + 8 * 1280 + 512];
  const int tid  = threadIdx.x;
  const int lane = tid & 63;
  const int wave = tid >> 6;
  const int wl = wave & 3;
  const int g  = wave >> 2;
  const int qx = blockIdx.x;
  const int h  = blockIdx.y & (H_HEADS - 1);
  const int b  = blockIdx.y >> 4;
  const int qt = b ? (15 - qx) : qx;
  const int r0 = qt * 64 + wl * 16;
  const size_t RS = 2 * E_DIM;
  const unsigned short* q  = qk + (size_t)b * T_SEQ * RS + (size_t)h * D_HEAD;
  const unsigned short* k  = q + E_DIM;
  const unsigned short* vb = vt + (size_t)(b * H_HEADS + h) * D_HEAD * T_SEQ;
  const size_t ybase = (size_t)b * T_SEQ * E_DIM + (size_t)h * D_HEAD;
  const int fr = lane & 15, fg = lane >> 4;
  const int srow = lane >> 3;
  const int ssw  = ((lane & 7) * 16) ^ (srow << 4);
  char* pb = smem + 32768 + wave * 1280;
  float* mlb = (float*)(smem + 32768 + 10240);

  short8 aq[2];
  #pragma unroll
  for (int c = 0; c < 2; ++c)
    aq[c] = *(const short8*)(q + (size_t)(r0 + fr) * RS + c * 32 + fg * 8);

  f32x4 oacc[4];
  #pragma unroll
  for (int cg = 0; cg < 4; ++cg) oacc[cg] = (f32x4){0.f, 0.f, 0.f, 0.f};
  float m_ = -1e30f, l_ = 0.0f;

  auto stage = [&](int t) {
    const int j0 = t * 64;
    char* Kd = smem + (t & 1) * 16384;
    GLDS16((const char*)k  + (size_t)(j0 + wave * 8 + srow) * RS * 2 + ssw,
           Kd + wave * 1024);
    GLDS16((const char*)vb + ((size_t)(wave * 8 + srow) * T_SEQ + j0) * 2 + ssw,
           Kd + 8192 + wave * 1024);
  };

  stage(0);
  for (int t = 0; t <= qt; ++t) {
    __builtin_amdgcn_sched_barrier(0);
    __builtin_amdgcn_s_barrier();
    if (t < qt) stage(t + 1);
    __builtin_amdgcn_sched_barrier(0);
    if (t < qt) asm volatile("s_waitcnt vmcnt(2)" ::: "memory");
    else        asm volatile("s_waitcnt vmcnt(0)" ::: "memory");
    __builtin_amdgcn_sched_barrier(0);
    __builtin_amdgcn_s_barrier();
    __builtin_amdgcn_sched_barrier(0);
    const char* Kl = smem + (t & 1) * 16384;
    const char* Vl = Kl + 8192;
    const int j0 = t * 64;
    if (!(t == qt && g == 1 && wl < 2)) {
      f32x4 st[2];
      #pragma unroll
      for (int cc = 0; cc < 2; ++cc) {
        const int kloc = g * 32 + cc * 16 + fr;
        const char* kb = Kl + kloc * 128;
        const int sw = (kloc & 7) << 4;
        short8 ka0 = *(const short8*)(kb + ((fg * 16) ^ sw));
        short8 ka1 = *(const short8*)(kb + ((64 + fg * 16) ^ sw));
        f32x4 z = (f32x4){0.f, 0.f, 0.f, 0.f};
        z = __builtin_amdgcn_mfma_f32_16x16x32_bf16(ka0, aq[0], z, 0, 0, 0);
        z = __builtin_amdgcn_mfma_f32_16x16x32_bf16(ka1, aq[1], z, 0, 0, 0);
        st[cc] = z;
      }
      const int qg = r0 + fr;
      float pv[2][4];
      float mx = -1e30f;
      #pragma unroll
      for (int cc = 0; cc < 2; ++cc)
        #pragma unroll
        for (int r = 0; r < 4; ++r) {
          const int kj = j0 + g * 32 + cc * 16 + fg * 4 + r;
          float val = (kj <= qg) ? st[cc][r] * 0.125f : -1e30f;
          pv[cc][r] = val;
          mx = fmaxf(mx, val);
        }
      mx = fmaxf(mx, __shfl_xor(mx, 16));
      mx = fmaxf(mx, __shfl_xor(mx, 32));
      const float mn = fmaxf(m_, mx);
      const float cfs = __expf(m_ - mn);
      float ls = 0.0f;
      #pragma unroll
      for (int cc = 0; cc < 2; ++cc) {
        ushort4 o;
        float e0 = pv[cc][0] > -1e29f ? __expf(pv[cc][0] - mn) : 0.0f;
        float e1 = pv[cc][1] > -1e29f ? __expf(pv[cc][1] - mn) : 0.0f;
        float e2 = pv[cc][2] > -1e29f ? __expf(pv[cc][2] - mn) : 0.0f;
        float e3 = pv[cc][3] > -1e29f ? __expf(pv[cc][3] - mn) : 0.0f;
        ls += (e0 + e1) + (e2 + e3);
        o.x = f2bf(e0); o.y = f2bf(e1); o.z = f2bf(e2); o.w = f2bf(e3);
        *(ushort4*)(pb + fr * 80 + cc * 32 + fg * 8) = o;
      }
      ls += __shfl_xor(ls, 16);
      ls += __shfl_xor(ls, 32);
      l_ = l_ * cfs + ls;
      m_ = mn;
      float cfO[4];
      #pragma unroll
      for (int r = 0; r < 4; ++r) cfO[r] = __shfl(cfs, (lane & 48) | (fg * 4 + r));
      asm volatile("s_waitcnt lgkmcnt(0)" ::: "memory");
      __builtin_amdgcn_sched_barrier(0);
      short8 pa = *(const short8*)(pb + fr * 80 + fg * 16);
      __builtin_amdgcn_s_setprio(1);
      #pragma unroll
      for (int cg = 0; cg < 4; ++cg) {
        const int d = cg * 16 + fr;
        short8 bv = *(const short8*)(Vl + d * 128 + ((g * 64 + fg * 16) ^ ((d & 7) << 4)));
        #pragma unroll
        for (int r = 0; r < 4; ++r) oacc[cg][r] *= cfO[r];
        oacc[cg] = __builtin_amdgcn_mfma_f32_16x16x32_bf16(pa, bv, oacc[cg], 0, 0, 0);
      }
      __builtin_amdgcn_s_setprio(0);
    }
  }
  __syncthreads();
  float* obuf = (float*)smem;
  if (g == 1) {
    #pragma unroll
    for (int cg = 0; cg < 4; ++cg)
      #pragma unroll
      for (int r = 0; r < 4; ++r)
        obuf[wl * 1024 + (fg * 4 + r) * 64 + cg * 16 + fr] = oacc[cg][r];
    if (fg == 0) { mlb[(wl * 16 + fr) * 2] = m_; mlb[(wl * 16 + fr) * 2 + 1] = l_; }
  }
  __syncthreads();
  if (g == 0) {
    const float m1 = mlb[(wl * 16 + fr) * 2];
    const float l1 = mlb[(wl * 16 + fr) * 2 + 1];
    const float m  = fmaxf(m_, m1);
    const float c0 = __expf(m_ - m), c1 = __expf(m1 - m);
    const float li = 1.0f / (l_ * c0 + l1 * c1);
    float c0O[4], c1O[4], liO[4];
    #pragma unroll
    for (int r = 0; r < 4; ++r) {
      const int src = (lane & 48) | (fg * 4 + r);
      c0O[r] = __shfl(c0, src); c1O[r] = __shfl(c1, src); liO[r] = __shfl(li, src);
    }
    #pragma unroll
    for (int cg = 0; cg < 4; ++cg)
      #pragma unroll
      for (int r = 0; r < 4; ++r) {
        const float o1 = obuf[wl * 1024 + (fg * 4 + r) * 64 + cg * 16 + fr];
        const float val = (oacc[cg][r] * c0O[r] + o1 * c1O[r]) * liO[r];
        y[ybase + (size_t)(r0 + fg * 4 + r) * E_DIM + cg * 16 + fr] = f2bf(val);
      }
  }
}

// ---------------- 128-tile bf16 GEMM, BK=64, 2-barrier (proj / MLP2) ----------------
template<int BM, int BN, bool HAS_BIAS, bool GELU_ACT, bool HAS_RES, int OMODE>
__global__ __launch_bounds__(256) void gemm_bt_kernel(
    const unsigned short* __restrict__ A, const unsigned short* __restrict__ Bt,
    const float* __restrict__ bias, const float* __restrict__ res,
    void* __restrict__ out, unsigned short* __restrict__ vt, int M, int N, int K) {
  constexpr int BK = 64;
  constexpr int MR = BM / 32;
  constexpr int NR = BN / 32;
  constexpr int AI = BM / 32;
  constexpr int BI = BN / 32;
  __shared__ __align__(16) char smem[(BM + BN) * BK * 2];   // As | Bs (and epilogue scratch)
  unsigned short* As = (unsigned short*)smem;
  unsigned short* Bs = (unsigned short*)(smem + (size_t)BM * BK * 2);
  const int tid  = threadIdx.x;
  const int lane = tid & 63;
  const int wave = tid >> 6;
  const int wr = wave >> 1, wc = wave & 1;

  const int mt = M / BM;
  const int q8 = gridDim.x >> 3;
  const int g  = (blockIdx.x & 7) * q8 + (blockIdx.x >> 3);
  const int m0 = (g % mt) * BM, n0 = (g / mt) * BN;

  const int fr = lane & 15, fg = lane >> 4;
  const int lrow = lane >> 3;
  const int scol = ((lane & 7) * 16) ^ (lrow << 4);
  const size_t K2 = (size_t)K * 2;
  const char* aG = (const char*)A  + (size_t)(m0 + wave * 8 + lrow) * K2 + scol;
  const char* bG = (const char*)Bt + (size_t)(n0 + wave * 8 + lrow) * K2 + scol;

  f32x4 acc[MR][NR];
  #pragma unroll
  for (int mi = 0; mi < MR; ++mi)
    #pragma unroll
    for (int ni = 0; ni < NR; ++ni) acc[mi][ni] = (f32x4){0.f, 0.f, 0.f, 0.f};

  for (int k0 = 0; k0 < K; k0 += BK) {
    __syncthreads();
    #pragma unroll
    for (int i = 0; i < AI; ++i)
      GLDS16(aG + (size_t)i * 32 * K2 + (size_t)k0 * 2, (char*)As + wave * 1024 + i * 4096);
    #pragma unroll
    for (int i = 0; i < BI; ++i)
      GLDS16(bG + (size_t)i * 32 * K2 + (size_t)k0 * 2, (char*)Bs + wave * 1024 + i * 4096);
    __syncthreads();

    short8 af[MR][2], bf[NR][2];
    #pragma unroll
    for (int mi = 0; mi < MR; ++mi) {
      const int row = wr * (BM / 2) + mi * 16 + fr;
      #pragma unroll
      for (int kh = 0; kh < 2; ++kh)
        af[mi][kh] = *(const short8*)((const char*)As + row * 128 +
                       ((kh * 64 + fg * 16) ^ ((row & 7) << 4)));
    }
    #pragma unroll
    for (int ni = 0; ni < NR; ++ni) {
      const int row = wc * (BN / 2) + ni * 16 + fr;
      #pragma unroll
      for (int kh = 0; kh < 2; ++kh)
        bf[ni][kh] = *(const short8*)((const char*)Bs + row * 128 +
                       ((kh * 64 + fg * 16) ^ ((row & 7) << 4)));
    }
    #pragma unroll
    for (int mi = 0; mi < MR; ++mi)
      #pragma unroll
      for (int ni = 0; ni < NR; ++ni) {
        acc[mi][ni] = __builtin_amdgcn_mfma_f32_16x16x32_bf16(af[mi][0], bf[ni][0], acc[mi][ni], 0, 0, 0);
        acc[mi][ni] = __builtin_amdgcn_mfma_f32_16x16x32_bf16(af[mi][1], bf[ni][1], acc[mi][ni], 0, 0, 0);
      }
  }

  if (OMODE == 0) {
    __syncthreads();   // all waves done with As/Bs fragments
    float* tw = (float*)(smem + wave * 4352);
    float bv4[NR];
    #pragma unroll
    for (int ni = 0; ni < NR; ++ni)
      bv4[ni] = HAS_BIAS ? bias[n0 + wc * (BN / 2) + ni * 16 + fr] : 0.0f;
    #pragma unroll
    for (int mi = 0; mi < MR; ++mi) {
      #pragma unroll
      for (int ni = 0; ni < NR; ++ni)
        #pragma unroll
        for (int r = 0; r < 4; ++r) {
          float val = acc[mi][ni][r] + bv4[ni];
          if (GELU_ACT) val = 0.5f * val * (1.0f + erff(val * 0.70710678118f));
          tw[(fg * 4 + r) * 68 + ni * 16 + fr] = val;
        }
      asm volatile("s_waitcnt lgkmcnt(0)" ::: "memory");
      __builtin_amdgcn_sched_barrier(0);
      #pragma unroll
      for (int rr = 0; rr < 4; ++rr) {
        const int row = rr * 4 + (lane >> 4);
        const int grow = m0 + wr * (BM / 2) + mi * 16 + row;
        const int gcol = n0 + wc * (BN / 2) + (lane & 15) * 4;
        f32x4 v = *(const f32x4*)&tw[row * 68 + (lane & 15) * 4];
        if (HAS_RES) v += *(const f32x4*)(res + (size_t)grow * N + gcol);
        *(f32x4*)((float*)out + (size_t)grow * N + gcol) = v;
      }
      asm volatile("s_waitcnt lgkmcnt(0)" ::: "memory");
      __builtin_amdgcn_sched_barrier(0);
    }
  } else {
    #pragma unroll
    for (int mi = 0; mi < MR; ++mi)
      #pragma unroll
      for (int ni = 0; ni < NR; ++ni) {
        const int col = n0 + wc * (BN / 2) + ni * 16 + fr;
        float bv = HAS_BIAS ? bias[col] : 0.0f;
        const int rbase = m0 + wr * (BM / 2) + mi * 16 + fg * 4;
        #pragma unroll
        for (int r = 0; r < 4; ++r) {
          float val = acc[mi][ni][r] + bv;
          if (GELU_ACT) val = 0.5f * val * (1.0f + erff(val * 0.70710678118f));
          ((unsigned short*)out)[(size_t)(rbase + r) * N + col] = f2bf(val);
        }
      }
  }
}

// ---------------- 128x256 8-phase bf16 GEMM (QKV / MLP1), T2+T3+T4+T5 ----------------
template<int OMODE, bool HAS_BIAS, bool GELU_ACT>
__global__ __launch_bounds__(512, 1) void gemm8p2_kernel(
    const unsigned short* __restrict__ A, const unsigned short* __restrict__ Bt,
    const float* __restrict__ bias, void* __restrict__ out,
    unsigned short* __restrict__ vt, int M, int N, int K) {
  __shared__ __align__(16) char lds[98304];
  const int tid  = threadIdx.x;
  const int lane = tid & 63;
  const int wv   = tid >> 6;
  const int wm = wv >> 2, wn = wv & 3;

  const int mt = M >> 7;
  const int q8 = gridDim.x >> 3;
  const int g  = (blockIdx.x & 7) * q8 + (blockIdx.x >> 3);
  const int m0 = (g % mt) * 128, n0 = (g / mt) * 256;

  const int fr = lane & 15, fg = lane >> 4;
  const size_t K2 = (size_t)K * 2;
  const int nIter = K >> 7;

  const int csw0 = (fg * 16) ^ ((fr & 7) << 4);
  const int csw1 = (64 + fg * 16) ^ ((fr & 7) << 4);

  const int sc = (lane * 16) & 127;
  const size_t laneoff = (size_t)(lane >> 3) * K2 + (size_t)(sc ^ ((lane >> 3) << 4));
  const char* Asrc = (const char*)(A + (size_t)m0 * K) + laneoff;
  const char* Bsrc = (const char*)(Bt + (size_t)n0 * K) + laneoff;
  const int arow_wv = (wv >> 2) * 64 + (wv & 3) * 8;
  const int brow_wv = (wv >> 2) * 64 + (wv & 3) * 8;

  f32x4 acc[4][4];
  #pragma unroll
  for (int i = 0; i < 4; ++i)
    #pragma unroll
    for (int j = 0; j < 4; ++j) acc[i][j] = (f32x4){0.f, 0.f, 0.f, 0.f};

  auto stageA = [&](int b, int c, int kt) {
    GLDS16(Asrc + (size_t)(arow_wv + c * 32) * K2 + (size_t)kt * 128,
           lds + b * 49152 + c * 8192 + wv * 1024);
  };
  auto stageB = [&](int b, int j, int kt) {
    GLDS16(Bsrc + (size_t)((j & 1) * 128 + (j >> 1) * 32 + brow_wv) * K2 + (size_t)kt * 128,
           lds + b * 49152 + 16384 + j * 8192 + wv * 1024);
  };

  stageA(0, 0, 0); stageA(0, 1, 0);
  stageB(0, 0, 0); stageB(0, 1, 0); stageB(0, 2, 0); stageB(0, 3, 0);
  stageA(1, 0, 1); stageB(1, 0, 1); stageB(1, 1, 1);
  __builtin_amdgcn_sched_barrier(0);
  asm volatile("s_waitcnt vmcnt(3)" ::: "memory");
  __builtin_amdgcn_s_barrier();

  for (int i = 0; i < nIter; ++i) {
    const bool last = (i == nIter - 1);
    #pragma unroll
    for (int p = 0; p < 8; ++p) {
      const int b  = p >> 2;
      const int mh = (p >> 1) & 1;
      const int nh = p & 1;
      const char* Ab = lds + b * 49152;
      const char* Bb = Ab + 16384;
      __builtin_amdgcn_sched_barrier(0);
      short8 fa[2][2], fb[2][2];
      #pragma unroll
      for (int j = 0; j < 2; ++j) {
        const int row = mh * 64 + wm * 32 + j * 16 + fr;
        fa[j][0] = *(const short8*)(Ab + row * 128 + csw0);
        fa[j][1] = *(const short8*)(Ab + row * 128 + csw1);
      }
      #pragma unroll
      for (int n = 0; n < 2; ++n) {
        const int row = nh * 128 + (wn >> 1) * 64 + (wn & 1) * 32 + n * 16 + fr;
        fb[n][0] = *(const short8*)(Bb + row * 128 + csw0);
        fb[n][1] = *(const short8*)(Bb + row * 128 + csw1);
      }
      if (p == 0) stageA(1, 1, 2 * i + 1);
      if (p == 1) { stageB(1, 2, 2 * i + 1); stageB(1, 3, 2 * i + 1); }
      if (!last) {
        if (p == 2) stageA(0, 0, 2 * i + 2);
        if (p == 3) { stageB(0, 0, 2 * i + 2); stageB(0, 1, 2 * i + 2); }
        if (p == 4) stageA(0, 1, 2 * i + 2);
        if (p == 5) { stageB(0, 2, 2 * i + 2); stageB(0, 3, 2 * i + 2); }
        if (p == 6) stageA(1, 0, 2 * i + 3);
        if (p == 7) { stageB(1, 0, 2 * i + 3); stageB(1, 1, 2 * i + 3); }
      }
      __builtin_amdgcn_sched_barrier(0);
      __builtin_amdgcn_s_barrier();
      __builtin_amdgcn_sched_barrier(0);
      __builtin_amdgcn_s_setprio(1);
      #pragma unroll
      for (int j = 0; j < 2; ++j)
        #pragma unroll
        for (int n = 0; n < 2; ++n) {
          acc[mh * 2 + j][nh * 2 + n] = __builtin_amdgcn_mfma_f32_16x16x32_bf16(
              fa[j][0], fb[n][0], acc[mh * 2 + j][nh * 2 + n], 0, 0, 0);
          acc[mh * 2 + j][nh * 2 + n] = __builtin_amdgcn_mfma_f32_16x16x32_bf16(
              fa[j][1], fb[n][1], acc[mh * 2 + j][nh * 2 + n], 0, 0, 0);
        }
      __builtin_amdgcn_s_setprio(0);
      __builtin_amdgcn_sched_barrier(0);
      if (p == 3) {
        if (!last) asm volatile("s_waitcnt vmcnt(3)" ::: "memory");
        else       asm volatile("s_waitcnt vmcnt(0)" ::: "memory");
      }
      if (p == 7 && !last)
        asm volatile("s_waitcnt vmcnt(3)" ::: "memory");
      __builtin_amdgcn_s_barrier();
    }
  }

  if (OMODE == 1) {
    unsigned short* tw = (unsigned short*)(lds + wv * 2176);
    float bv4[4];
    #pragma unroll
    for (int ni = 0; ni < 4; ++ni)
      bv4[ni] = HAS_BIAS ? bias[n0 + wn * 64 + ni * 16 + fr] : 0.0f;
    #pragma unroll
    for (int mi = 0; mi < 4; ++mi) {
      #pragma unroll
      for (int ni = 0; ni < 4; ++ni)
        #pragma unroll
        for (int r = 0; r < 4; ++r) {
          float val = acc[mi][ni][r] + bv4[ni];
          if (GELU_ACT) val = 0.5f * val * (1.0f + erff(val * 0.70710678118f));
          tw[(fg * 4 + r) * 68 + ni * 16 + fr] = f2bf(val);
        }
      asm volatile("s_waitcnt lgkmcnt(0)" ::: "memory");
      __builtin_amdgcn_sched_barrier(0);
      #pragma unroll
      for (int rr = 0; rr < 4; ++rr) {
        const int row = rr * 4 + (lane >> 4);
        const int grow = m0 + wm * 64 + mi * 16 + row;
        const int gcol = n0 + wn * 64 + (lane & 15) * 4;
        ushort4 v = *(const ushort4*)&tw[row * 68 + (lane & 15) * 4];
        *(ushort4*)((unsigned short*)out + (size_t)grow * N + gcol) = v;
      }
      asm volatile("s_waitcnt lgkmcnt(0)" ::: "memory");
      __builtin_amdgcn_sched_barrier(0);
    }
  } else {
    #pragma unroll
    for (int mi = 0; mi < 4; ++mi) {
      #pragma unroll
      for (int ni = 0; ni < 4; ++ni) {
        const int col = n0 + wn * 64 + ni * 16 + fr;
        float bv = HAS_BIAS ? bias[col] : 0.0f;
        const int rbase = m0 + wm * 64 + mi * 16 + fg * 4;
        float vals[4];
        #pragma unroll
        for (int r = 0; r < 4; ++r) vals[r] = acc[mi][ni][r] + bv;
        if (col < 2 * E_DIM) {
          #pragma unroll
          for (int r = 0; r < 4; ++r)
            ((unsigned short*)out)[(size_t)(rbase + r) * 2 * E_DIM + col] = f2bf(vals[r]);
        } else {
          const int c2 = col - 2 * E_DIM;
          const int hh = c2 >> 6, d = c2 & 63;
          const int bb = rbase >> 10, t0 = rbase & (T_SEQ - 1);
          ushort4 o;
          o.x = f2bf(vals[0]); o.y = f2bf(vals[1]);
          o.z = f2bf(vals[2]); o.w = f2bf(vals[3]);
          *(ushort4*)(vt + ((size_t)(bb * H_HEADS + hh) * D_HEAD + d) * T_SEQ + t0) = o;
        }
      }
    }
  }
}

// ---------------- persistent 256x256 8-phase bf16 GEMM (LM head) ----------------
// Grid = 256 blocks; each block owns ~4 (m,n) tiles of its XCD's contiguous
// range. The steady-state schedule stages kt=16,17 at iter-7 -> those loads are
// redirected to the NEXT work item's kt0,kt1, so the pipeline never drains
// across tile boundaries; gate arithmetic (vmcnt(4) @ p3/p7) is unchanged.
// Epilogue = direct stores (no LDS scratch; buffers hold next-tile data).
__global__ __launch_bounds__(512, 1) void gemm8p_kernel(
    const unsigned short* __restrict__ A, const unsigned short* __restrict__ Bt,
    const float* __restrict__ bias, float* __restrict__ out, int M, int N, int K) {
  __shared__ __align__(16) char lds[131072];
  const int tid  = threadIdx.x;
  const int lane = tid & 63;
  const int wv   = tid >> 6;
  const int wm = wv >> 2, wn = wv & 3;
  const int fr = lane & 15, fg = lane >> 4;
  const size_t K2 = (size_t)K * 2;
  const int nIter = K >> 7;            // 8 (K=1024)
  const int mt = M >> 8;               // 8
  const int perX = (mt * (N >> 8)) >> 3;  // 125
  const int xcd = blockIdx.x & 7, local = blockIdx.x >> 3;

  const int csw0 = (fg * 16) ^ ((fr & 7) << 4);
  const int csw1 = (64 + fg * 16) ^ ((fr & 7) << 4);
  const int sc = (lane * 16) & 127;
  const size_t laneoff = (size_t)(lane >> 3) * K2 + (size_t)(sc ^ ((lane >> 3) << 4));

  auto srcA = [&](int g) {
    return (const char*)(A + (size_t)((g % mt) * 256) * K) + (size_t)(wv * 8) * K2 + laneoff;
  };
  auto srcB = [&](int g) {
    return (const char*)(Bt + (size_t)((g / mt) * 256) * K) + laneoff;
  };
  auto stageA = [&](const char* S, int b, int q, int kt) {
    GLDS16(S + (size_t)(q * 64) * K2 + (size_t)kt * 128,
           lds + b * 65536 + q * 8192 + wv * 1024);
  };
  auto stageB = [&](const char* S, int b, int j, int o, int kt) {
    const int gw = j * 64 + wv * 8;
    const int rw = ((gw >> 5) << 6) + (gw & 31) + o * 32;
    GLDS16(S + (size_t)rw * K2 + (size_t)kt * 128,
           lds + b * 65536 + 32768 + rw * 128);
  };

  f32x4 acc[8][4];
  #pragma unroll
  for (int i = 0; i < 8; ++i)
    #pragma unroll
    for (int j = 0; j < 4; ++j) acc[i][j] = (f32x4){0.f, 0.f, 0.f, 0.f};

  int g = xcd * perX + local;
  const char* Ac = srcA(g);
  const char* Bc = srcB(g);

  // prologue: buf0 <- kt0 full, buf1 <- kt1 first half (first work item)
  stageA(Ac, 0, 0, 0); stageA(Ac, 0, 2, 0);
  stageB(Bc, 0, 0, 0, 0); stageB(Bc, 0, 1, 0, 0);
  stageA(Ac, 0, 1, 0); stageA(Ac, 0, 3, 0);
  stageB(Bc, 0, 0, 1, 0); stageB(Bc, 0, 1, 1, 0);
  stageA(Ac, 1, 0, 1); stageA(Ac, 1, 2, 1);
  stageB(Bc, 1, 0, 0, 1); stageB(Bc, 1, 1, 0, 1);
  __builtin_amdgcn_sched_barrier(0);
  asm volatile("s_waitcnt vmcnt(4)" ::: "memory");
  __builtin_amdgcn_s_barrier();

  for (int w = local; w < perX; w += 32) {
    const bool finalW = (w + 32 >= perX);
    const int gN = finalW ? g : (g + 32);
    const char* An = srcA(gN);
    const char* Bn = srcB(gN);
    const int m0 = (g % mt) * 256, n0 = (g / mt) * 256;

    for (int i = 0; i < nIter; ++i) {
      const bool wrap = (i == nIter - 1);
      const bool skip = wrap && finalW;
      const char* Aw = wrap ? An : Ac;     // source for kt 2i+2 / 2i+3 staging
      const char* Bw = wrap ? Bn : Bc;
      const int kt2 = wrap ? 0 : (2 * i + 2);
      const int kt3 = wrap ? 1 : (2 * i + 3);
      #pragma unroll
      for (int p = 0; p < 8; ++p) {
        const int b  = p >> 2;
        const int mh = (p & 3) >> 1;
        const int nh = p & 1;
        const char* Ab = lds + b * 65536;
        const char* Bb = Ab + 32768;
        __builtin_amdgcn_sched_barrier(0);
        short8 fa[4][2], fb[2][2];
        #pragma unroll
        for (int j = 0; j < 4; ++j) {
          const int row = wm * 128 + mh * 64 + j * 16 + fr;
          fa[j][0] = *(const short8*)(Ab + row * 128 + csw0);
          fa[j][1] = *(const short8*)(Ab + row * 128 + csw1);
        }
        #pragma unroll
        for (int n = 0; n < 2; ++n) {
          const int row = wn * 64 + nh * 32 + n * 16 + fr;
          fb[n][0] = *(const short8*)(Bb + row * 128 + csw0);
          fb[n][1] = *(const short8*)(Bb + row * 128 + csw1);
        }
        if (p == 0) { stageA(Ac, 1, 1, 2 * i + 1); stageA(Ac, 1, 3, 2 * i + 1); }
        if (p == 1) { stageB(Bc, 1, 0, 1, 2 * i + 1); stageB(Bc, 1, 1, 1, 2 * i + 1); }
        if (!skip) {
          if (p == 2) { stageA(Aw, 0, 0, kt2); stageA(Aw, 0, 2, kt2); }
          if (p == 3) { stageB(Bw, 0, 0, 0, kt2); stageB(Bw, 0, 1, 0, kt2); }
          if (p == 4) { stageA(Aw, 0, 1, kt2); stageA(Aw, 0, 3, kt2); }
          if (p == 5) { stageB(Bw, 0, 0, 1, kt2); stageB(Bw, 0, 1, 1, kt2); }
          if (p == 6) { stageA(Aw, 1, 0, kt3); stageA(Aw, 1, 2, kt3); }
          if (p == 7) { stageB(Bw, 1, 0, 0, kt3); stageB(Bw, 1, 1, 0, kt3); }
        }
        __builtin_amdgcn_sched_barrier(0);
        __builtin_amdgcn_s_barrier();
        __builtin_amdgcn_sched_barrier(0);
        __builtin_amdgcn_s_setprio(1);
        #pragma unroll
        for (int j = 0; j < 4; ++j)
          #pragma unroll
          for (int n = 0; n < 2; ++n) {
            acc[mh * 4 + j][nh * 2 + n] = __builtin_amdgcn_mfma_f32_16x16x32_bf16(
                fa[j][0], fb[n][0], acc[mh * 4 + j][nh * 2 + n], 0, 0, 0);
            acc[mh * 4 + j][nh * 2 + n] = __builtin_amdgcn_mfma_f32_16x16x32_bf16(
                fa[j][1], fb[n][1], acc[mh * 4 + j][nh * 2 + n], 0, 0, 0);
          }
        __builtin_amdgcn_s_setprio(0);
        __builtin_amdgcn_sched_barrier(0);
        if (p == 3) {
          if (!skip) asm volatile("s_waitcnt vmcnt(4)" ::: "memory");
          else       asm volatile("s_waitcnt vmcnt(0)" ::: "memory");
        }
        if (p == 7 && !skip)
          asm volatile("s_waitcnt vmcnt(4)" ::: "memory");
        __builtin_amdgcn_s_barrier();
      }
    }

    // epilogue: direct stores from accs (no LDS), then reset accs
    #pragma unroll
    for (int mi = 0; mi < 8; ++mi) {
      #pragma unroll
      for (int ni = 0; ni < 4; ++ni) {
        const int col = n0 + wn * 64 + ni * 16 + fr;
        const float bv = bias[col];
        #pragma unroll
        for (int r = 0; r < 4; ++r) {
          const int row = m0 + wm * 128 + mi * 16 + fg * 4 + r;
          out[(size_t)row * N + col] = acc[mi][ni][r] + bv;
          acc[mi][ni][r] = 0.0f;
        }
      }
    }
    g = gN; Ac = An; Bc = Bn;
  }
}

extern "C" void kernel_launch(void* const* d_in, const int* in_sizes, int n_in,
                              void* d_out, int out_size, void* d_ws, size_t ws_size,
                              hipStream_t stream) {
  const int*   idx   = (const int*)  d_in[0];
  const float* tok_w = (const float*)d_in[1];
  const float* pos_w = (const float*)d_in[2];
  const float* ln1_g = (const float*)d_in[3];
  const float* ln1_b = (const float*)d_in[4];
  const float* wq    = (const float*)d_in[5];
  const float* wk    = (const float*)d_in[6];
  const float* wv    = (const float*)d_in[7];
  const float* wp    = (const float*)d_in[8];
  const float* bp    = (const float*)d_in[9];
  const float* ln2_g = (const float*)d_in[10];
  const float* ln2_b = (const float*)d_in[11];
  const float* w1    = (const float*)d_in[12];
  const float* b1    = (const float*)d_in[13];
  const float* w2    = (const float*)d_in[14];
  const float* b2    = (const float*)d_in[15];
  const float* lnf_g = (const float*)d_in[16];
  const float* lnf_b = (const float*)d_in[17];
  const float* wlm   = (const float*)d_in[18];
  const float* blm   = (const float*)d_in[19];

  const int M = B_BATCH * T_SEQ;  // 2048
  const size_t EE = (size_t)E_DIM * E_DIM;
  const size_t EF = (size_t)E_DIM * F_DIM;
  char* p = (char*)d_ws;
  float* x            = (float*)p;          p += (size_t)M * E_DIM * 4;
  unsigned short* hb  = (unsigned short*)p; p += (size_t)M * E_DIM * 2;
  unsigned short* qkb = (unsigned short*)p; p += (size_t)M * 2 * E_DIM * 2;
  unsigned short* vtb = (unsigned short*)p; p += (size_t)M * E_DIM * 2;
  unsigned short* yb  = (unsigned short*)p; p += (size_t)M * E_DIM * 2;
  unsigned short* tb  = (unsigned short*)p; p += (size_t)M * F_DIM * 2;
  unsigned short* wtb = (unsigned short*)p; p += (size_t)V_VOCAB * E_DIM * 2;

  embed_kernel<<<M * E_DIM / 4 / 256, 256, 0, stream>>>(idx, tok_w, pos_w, x);

  for (int l = 0; l < L_LAYERS; ++l) {
    wtrans6ln_kernel<<<5120, 256, 0, stream>>>(
        wq + l * EE, wk + l * EE, wv + l * EE, wp + l * EE,
        w1 + l * EF, w2 + l * EF,
        ln1_g + (size_t)l * E_DIM, ln1_b + (size_t)l * E_DIM, x, wtb, hb);
    gemm8p2_kernel<2, false, false>
        <<<(M / 128) * (3 * E_DIM / 256), 512, 0, stream>>>(
        hb, wtb, nullptr, qkb, vtb, M, 3 * E_DIM, E_DIM);
    attn_mfma_kernel<<<dim3(16, B_BATCH * H_HEADS), 512, 0, stream>>>(qkb, vtb, yb);
    gemm_bt_kernel<64, 128, true, false, true, 0>
        <<<(M / 64) * (E_DIM / 128), 256, 0, stream>>>(
        yb, wtb + 3 * EE, bp + (size_t)l * E_DIM, x, x, nullptr, M, E_DIM, E_DIM);
    ln_kernel<<<M, 256, 0, stream>>>(x, ln2_g + (size_t)l * E_DIM, ln2_b + (size_t)l * E_DIM, hb);
    gemm8p2_kernel<1, true, true>
        <<<(M / 128) * (F_DIM / 256), 512, 0, stream>>>(
        hb, wtb + 4 * EE, b1 + (size_t)l * F_DIM, tb, nullptr, M, F_DIM, E_DIM);
    gemm_bt_kernel<64, 128, true, false, true, 0>
        <<<(M / 64) * (E_DIM / 128), 256, 0, stream>>>(
        tb, wtb + 4 * EE + EF, b2 + (size_t)l * E_DIM, x, x, nullptr, M, E_DIM, F_DIM);
  }
  wtransv_ln_kernel<<<10048, 256, 0, stream>>>(wlm, lnf_g, lnf_b, x, wtb, hb);
  gemm8p_kernel<<<256, 512, 0, stream>>>(
      hb, wtb, blm, (float*)d_out, M, V_VOCAB, E_DIM);
}

// Round 14
// 1192.339 us; speedup vs baseline: 1.0948x; 1.0948x over previous
//
#include <hip/hip_runtime.h>

#define T_SEQ   1024
#define E_DIM   1024
#define H_HEADS 16
#define D_HEAD  64
#define L_LAYERS 6
#define B_BATCH 2
#define F_DIM   4096
#define V_VOCAB 32000

typedef float f32x4 __attribute__((ext_vector_type(4)));
typedef short short8 __attribute__((ext_vector_type(8)));

__device__ __forceinline__ unsigned short f2bf(float f) {
  union { float f; unsigned int u; } v; v.f = f;
  unsigned int r = v.u + 0x7fffu + ((v.u >> 16) & 1u);  // RNE
  return (unsigned short)(r >> 16);
}

// async global->LDS, 16B per lane; lds dest = wave-uniform base + lane*16
#define GLDS16(gp, lp) __builtin_amdgcn_global_load_lds( \
    (const __attribute__((address_space(1))) void*)(gp), \
    (__attribute__((address_space(3))) void*)(lp), 16, 0, 0)

// ---------------- embedding: x = tok_w[idx] + pos_w ----------------
__global__ void embed_kernel(const int* __restrict__ idx, const float* __restrict__ tok,
                             const float* __restrict__ pos, float* __restrict__ x) {
  int i = blockIdx.x * 256 + threadIdx.x;
  int bt = i >> 8;
  int e4 = i & 255;
  int t  = bt & (T_SEQ - 1);
  int tokid = idx[bt];
  f32x4 a = *(const f32x4*)(tok + (size_t)tokid * E_DIM + e4 * 4);
  f32x4 p = *(const f32x4*)(pos + (size_t)t * E_DIM + e4 * 4);
  *(f32x4*)(x + (size_t)bt * E_DIM + e4 * 4) = a + p;
}

// ---------------- layernorm body (f32 in, bf16 out), 256 threads ----------------
__device__ __forceinline__ void ln_body(const float* __restrict__ x,
    const float* __restrict__ g, const float* __restrict__ b,
    unsigned short* __restrict__ out, int row) {
  int tid = threadIdx.x;
  const float* xr = x + (size_t)row * E_DIM;
  f32x4 v = *(const f32x4*)(xr + tid * 4);
  float s  = v[0] + v[1] + v[2] + v[3];
  float s2 = v[0]*v[0] + v[1]*v[1] + v[2]*v[2] + v[3]*v[3];
  #pragma unroll
  for (int off = 32; off > 0; off >>= 1) {
    s  += __shfl_xor(s,  off);
    s2 += __shfl_xor(s2, off);
  }
  __shared__ float red[2][4];
  int wave = tid >> 6;
  if ((tid & 63) == 0) { red[0][wave] = s; red[1][wave] = s2; }
  __syncthreads();
  s  = red[0][0] + red[0][1] + red[0][2] + red[0][3];
  s2 = red[1][0] + red[1][1] + red[1][2] + red[1][3];
  float mean = s * (1.0f / E_DIM);
  float var  = s2 * (1.0f / E_DIM) - mean * mean;
  float rstd = rsqrtf(var + 1e-5f);
  f32x4 gv = *(const f32x4*)(g + tid * 4);
  f32x4 bv = *(const f32x4*)(b + tid * 4);
  ushort4 o;
  o.x = f2bf((v[0] - mean) * rstd * gv[0] + bv[0]);
  o.y = f2bf((v[1] - mean) * rstd * gv[1] + bv[1]);
  o.z = f2bf((v[2] - mean) * rstd * gv[2] + bv[2]);
  o.w = f2bf((v[3] - mean) * rstd * gv[3] + bv[3]);
  *(ushort4*)(out + (size_t)row * E_DIM + tid * 4) = o;
}

__global__ void ln_kernel(const float* __restrict__ x, const float* __restrict__ g,
                          const float* __restrict__ b, unsigned short* __restrict__ out) {
  ln_body(x, g, b, out, blockIdx.x);
}

// ---------------- weight transpose+convert: W f32 [K][N] -> Wt bf16 [N][K] ----------------
__device__ __forceinline__ void wtrans_body(const float* __restrict__ W,
    unsigned short* __restrict__ Wt, int K, int N, int bx, int by) {
  __shared__ float tile[64][65];
  const int n0 = bx * 64, k0 = by * 64;
  const int tr  = threadIdx.x >> 4;
  const int tc4 = (threadIdx.x & 15) * 4;
  #pragma unroll
  for (int p = 0; p < 4; ++p) {
    f32x4 v = *(const f32x4*)(W + (size_t)(k0 + p * 16 + tr) * N + n0 + tc4);
    tile[p * 16 + tr][tc4 + 0] = v[0];
    tile[p * 16 + tr][tc4 + 1] = v[1];
    tile[p * 16 + tr][tc4 + 2] = v[2];
    tile[p * 16 + tr][tc4 + 3] = v[3];
  }
  __syncthreads();
  #pragma unroll
  for (int p = 0; p < 4; ++p) {
    int n = p * 16 + tr;
    ushort4 o;
    o.x = f2bf(tile[tc4 + 0][n]);
    o.y = f2bf(tile[tc4 + 1][n]);
    o.z = f2bf(tile[tc4 + 2][n]);
    o.w = f2bf(tile[tc4 + 3][n]);
    *(ushort4*)(Wt + (size_t)(n0 + n) * K + k0 + tc4) = o;
  }
}

// layer weights (q,k,v,p,w1,w2) + ln1 in one launch; grid = 3072 + 2048
__global__ __launch_bounds__(256) void wtrans6ln_kernel(const float* __restrict__ wq,
    const float* __restrict__ wk, const float* __restrict__ wv, const float* __restrict__ wp,
    const float* __restrict__ w1, const float* __restrict__ w2,
    const float* __restrict__ lng, const float* __restrict__ lnb,
    const float* __restrict__ x, unsigned short* __restrict__ wtb,
    unsigned short* __restrict__ hb) {
  const size_t EE = (size_t)E_DIM * E_DIM;
  const size_t EF = (size_t)E_DIM * F_DIM;
  const int id = blockIdx.x;
  if (id < 1024) {
    const int z = id >> 8, r = id & 255;
    const float* W = z == 0 ? wq : (z == 1 ? wk : (z == 2 ? wv : wp));
    wtrans_body(W, wtb + z * EE, E_DIM, E_DIM, r & 15, r >> 4);
  } else if (id < 2048) {
    const int r = id - 1024;
    wtrans_body(w1, wtb + 4 * EE, E_DIM, F_DIM, r & 63, r >> 6);
  } else if (id < 3072) {
    const int r = id - 2048;
    wtrans_body(w2, wtb + 4 * EE + EF, F_DIM, E_DIM, r & 15, r >> 4);
  } else {
    ln_body(x, lng, lnb, hb, id - 3072);
  }
}

// LM weight transpose + final layernorm; grid = 8000 + 2048
__global__ __launch_bounds__(256) void wtransv_ln_kernel(const float* __restrict__ wlm,
    const float* __restrict__ lng, const float* __restrict__ lnb,
    const float* __restrict__ x, unsigned short* __restrict__ wtb,
    unsigned short* __restrict__ hb) {
  const int id = blockIdx.x;
  if (id < 8000) wtrans_body(wlm, wtb, E_DIM, V_VOCAB, id % 500, id / 500);
  else           ln_body(x, lng, lnb, hb, id - 8000);
}

// ---------------- MFMA flash attention, split-key, all-waves-busy ----------------
__global__ __launch_bounds__(512) void attn_mfma_kernel(
    const unsigned short* __restrict__ qk, const unsigned short* __restrict__ vt,
    unsigned short* __restrict__ y) {
  __shared__ __align__(16) char smem[2 * 16384 + 8 * 1280 + 512];
  const int tid  = threadIdx.x;
  const int lane = tid & 63;
  const int wave = tid >> 6;
  const int wl = wave & 3;
  const int g  = wave >> 2;
  const int qx = blockIdx.x;
  const int h  = blockIdx.y & (H_HEADS - 1);
  const int b  = blockIdx.y >> 4;
  const int qt = b ? (15 - qx) : qx;
  const int r0 = qt * 64 + wl * 16;
  const size_t RS = 2 * E_DIM;
  const unsigned short* q  = qk + (size_t)b * T_SEQ * RS + (size_t)h * D_HEAD;
  const unsigned short* k  = q + E_DIM;
  const unsigned short* vb = vt + (size_t)(b * H_HEADS + h) * D_HEAD * T_SEQ;
  const size_t ybase = (size_t)b * T_SEQ * E_DIM + (size_t)h * D_HEAD;
  const int fr = lane & 15, fg = lane >> 4;
  const int srow = lane >> 3;
  const int ssw  = ((lane & 7) * 16) ^ (srow << 4);
  char* pb = smem + 32768 + wave * 1280;
  float* mlb = (float*)(smem + 32768 + 10240);

  short8 aq[2];
  #pragma unroll
  for (int c = 0; c < 2; ++c)
    aq[c] = *(const short8*)(q + (size_t)(r0 + fr) * RS + c * 32 + fg * 8);

  f32x4 oacc[4];
  #pragma unroll
  for (int cg = 0; cg < 4; ++cg) oacc[cg] = (f32x4){0.f, 0.f, 0.f, 0.f};
  float m_ = -1e30f, l_ = 0.0f;

  auto stage = [&](int t) {
    const int j0 = t * 64;
    char* Kd = smem + (t & 1) * 16384;
    GLDS16((const char*)k  + (size_t)(j0 + wave * 8 + srow) * RS * 2 + ssw,
           Kd + wave * 1024);
    GLDS16((const char*)vb + ((size_t)(wave * 8 + srow) * T_SEQ + j0) * 2 + ssw,
           Kd + 8192 + wave * 1024);
  };

  stage(0);
  for (int t = 0; t <= qt; ++t) {
    __builtin_amdgcn_sched_barrier(0);
    __builtin_amdgcn_s_barrier();
    if (t < qt) stage(t + 1);
    __builtin_amdgcn_sched_barrier(0);
    if (t < qt) asm volatile("s_waitcnt vmcnt(2)" ::: "memory");
    else        asm volatile("s_waitcnt vmcnt(0)" ::: "memory");
    __builtin_amdgcn_sched_barrier(0);
    __builtin_amdgcn_s_barrier();
    __builtin_amdgcn_sched_barrier(0);
    const char* Kl = smem + (t & 1) * 16384;
    const char* Vl = Kl + 8192;
    const int j0 = t * 64;
    if (!(t == qt && g == 1 && wl < 2)) {
      f32x4 st[2];
      #pragma unroll
      for (int cc = 0; cc < 2; ++cc) {
        const int kloc = g * 32 + cc * 16 + fr;
        const char* kb = Kl + kloc * 128;
        const int sw = (kloc & 7) << 4;
        short8 ka0 = *(const short8*)(kb + ((fg * 16) ^ sw));
        short8 ka1 = *(const short8*)(kb + ((64 + fg * 16) ^ sw));
        f32x4 z = (f32x4){0.f, 0.f, 0.f, 0.f};
        z = __builtin_amdgcn_mfma_f32_16x16x32_bf16(ka0, aq[0], z, 0, 0, 0);
        z = __builtin_amdgcn_mfma_f32_16x16x32_bf16(ka1, aq[1], z, 0, 0, 0);
        st[cc] = z;
      }
      const int qg = r0 + fr;
      float pv[2][4];
      float mx = -1e30f;
      #pragma unroll
      for (int cc = 0; cc < 2; ++cc)
        #pragma unroll
        for (int r = 0; r < 4; ++r) {
          const int kj = j0 + g * 32 + cc * 16 + fg * 4 + r;
          float val = (kj <= qg) ? st[cc][r] * 0.125f : -1e30f;
          pv[cc][r] = val;
          mx = fmaxf(mx, val);
        }
      mx = fmaxf(mx, __shfl_xor(mx, 16));
      mx = fmaxf(mx, __shfl_xor(mx, 32));
      const float mn = fmaxf(m_, mx);
      const float cfs = __expf(m_ - mn);
      float ls = 0.0f;
      #pragma unroll
      for (int cc = 0; cc < 2; ++cc) {
        ushort4 o;
        float e0 = pv[cc][0] > -1e29f ? __expf(pv[cc][0] - mn) : 0.0f;
        float e1 = pv[cc][1] > -1e29f ? __expf(pv[cc][1] - mn) : 0.0f;
        float e2 = pv[cc][2] > -1e29f ? __expf(pv[cc][2] - mn) : 0.0f;
        float e3 = pv[cc][3] > -1e29f ? __expf(pv[cc][3] - mn) : 0.0f;
        ls += (e0 + e1) + (e2 + e3);
        o.x = f2bf(e0); o.y = f2bf(e1); o.z = f2bf(e2); o.w = f2bf(e3);
        *(ushort4*)(pb + fr * 80 + cc * 32 + fg * 8) = o;
      }
      ls += __shfl_xor(ls, 16);
      ls += __shfl_xor(ls, 32);
      l_ = l_ * cfs + ls;
      m_ = mn;
      float cfO[4];
      #pragma unroll
      for (int r = 0; r < 4; ++r) cfO[r] = __shfl(cfs, (lane & 48) | (fg * 4 + r));
      asm volatile("s_waitcnt lgkmcnt(0)" ::: "memory");
      __builtin_amdgcn_sched_barrier(0);
      short8 pa = *(const short8*)(pb + fr * 80 + fg * 16);
      __builtin_amdgcn_s_setprio(1);
      #pragma unroll
      for (int cg = 0; cg < 4; ++cg) {
        const int d = cg * 16 + fr;
        short8 bv = *(const short8*)(Vl + d * 128 + ((g * 64 + fg * 16) ^ ((d & 7) << 4)));
        #pragma unroll
        for (int r = 0; r < 4; ++r) oacc[cg][r] *= cfO[r];
        oacc[cg] = __builtin_amdgcn_mfma_f32_16x16x32_bf16(pa, bv, oacc[cg], 0, 0, 0);
      }
      __builtin_amdgcn_s_setprio(0);
    }
  }
  __syncthreads();
  float* obuf = (float*)smem;
  if (g == 1) {
    #pragma unroll
    for (int cg = 0; cg < 4; ++cg)
      #pragma unroll
      for (int r = 0; r < 4; ++r)
        obuf[wl * 1024 + (fg * 4 + r) * 64 + cg * 16 + fr] = oacc[cg][r];
    if (fg == 0) { mlb[(wl * 16 + fr) * 2] = m_; mlb[(wl * 16 + fr) * 2 + 1] = l_; }
  }
  __syncthreads();
  if (g == 0) {
    const float m1 = mlb[(wl * 16 + fr) * 2];
    const float l1 = mlb[(wl * 16 + fr) * 2 + 1];
    const float m  = fmaxf(m_, m1);
    const float c0 = __expf(m_ - m), c1 = __expf(m1 - m);
    const float li = 1.0f / (l_ * c0 + l1 * c1);
    float c0O[4], c1O[4], liO[4];
    #pragma unroll
    for (int r = 0; r < 4; ++r) {
      const int src = (lane & 48) | (fg * 4 + r);
      c0O[r] = __shfl(c0, src); c1O[r] = __shfl(c1, src); liO[r] = __shfl(li, src);
    }
    #pragma unroll
    for (int cg = 0; cg < 4; ++cg)
      #pragma unroll
      for (int r = 0; r < 4; ++r) {
        const float o1 = obuf[wl * 1024 + (fg * 4 + r) * 64 + cg * 16 + fr];
        const float val = (oacc[cg][r] * c0O[r] + o1 * c1O[r]) * liO[r];
        y[ybase + (size_t)(r0 + fg * 4 + r) * E_DIM + cg * 16 + fr] = f2bf(val);
      }
  }
}

// ---------------- 64x64 bf16 GEMM, BK=64, 2-barrier, grid 512 (2 blocks/CU) ----------------
// proj / MLP2: f32 out + res, coalesced LDS-transposed epilogue ([16][36] f32/wave).
template<bool HAS_BIAS, bool GELU_ACT, bool HAS_RES>
__global__ __launch_bounds__(256) void gemm_bt_kernel(
    const unsigned short* __restrict__ A, const unsigned short* __restrict__ Bt,
    const float* __restrict__ bias, const float* __restrict__ res,
    float* __restrict__ out, int M, int N, int K) {
  constexpr int BM = 64, BN = 64, BK = 64;
  constexpr int MR = 2, NR = 2;
  __shared__ __align__(16) char smem[(BM + BN) * BK * 2];   // As | Bs, epilogue scratch
  unsigned short* As = (unsigned short*)smem;
  unsigned short* Bs = (unsigned short*)(smem + BM * BK * 2);
  const int tid  = threadIdx.x;
  const int lane = tid & 63;
  const int wave = tid >> 6;
  const int wr = wave >> 1, wc = wave & 1;

  const int mt = M / BM;
  const int q8 = gridDim.x >> 3;
  const int g  = (blockIdx.x & 7) * q8 + (blockIdx.x >> 3);
  const int m0 = (g % mt) * BM, n0 = (g / mt) * BN;

  const int fr = lane & 15, fg = lane >> 4;
  const int lrow = lane >> 3;
  const int scol = ((lane & 7) * 16) ^ (lrow << 4);
  const size_t K2 = (size_t)K * 2;
  const char* aG = (const char*)A  + (size_t)(m0 + wave * 8 + lrow) * K2 + scol;
  const char* bG = (const char*)Bt + (size_t)(n0 + wave * 8 + lrow) * K2 + scol;

  f32x4 acc[MR][NR];
  #pragma unroll
  for (int mi = 0; mi < MR; ++mi)
    #pragma unroll
    for (int ni = 0; ni < NR; ++ni) acc[mi][ni] = (f32x4){0.f, 0.f, 0.f, 0.f};

  for (int k0 = 0; k0 < K; k0 += BK) {
    __syncthreads();
    #pragma unroll
    for (int i = 0; i < 2; ++i)
      GLDS16(aG + (size_t)i * 32 * K2 + (size_t)k0 * 2, (char*)As + wave * 1024 + i * 4096);
    #pragma unroll
    for (int i = 0; i < 2; ++i)
      GLDS16(bG + (size_t)i * 32 * K2 + (size_t)k0 * 2, (char*)Bs + wave * 1024 + i * 4096);
    __syncthreads();

    short8 af[MR][2], bf[NR][2];
    #pragma unroll
    for (int mi = 0; mi < MR; ++mi) {
      const int row = wr * 32 + mi * 16 + fr;
      #pragma unroll
      for (int kh = 0; kh < 2; ++kh)
        af[mi][kh] = *(const short8*)((const char*)As + row * 128 +
                       ((kh * 64 + fg * 16) ^ ((row & 7) << 4)));
    }
    #pragma unroll
    for (int ni = 0; ni < NR; ++ni) {
      const int row = wc * 32 + ni * 16 + fr;
      #pragma unroll
      for (int kh = 0; kh < 2; ++kh)
        bf[ni][kh] = *(const short8*)((const char*)Bs + row * 128 +
                       ((kh * 64 + fg * 16) ^ ((row & 7) << 4)));
    }
    #pragma unroll
    for (int mi = 0; mi < MR; ++mi)
      #pragma unroll
      for (int ni = 0; ni < NR; ++ni) {
        acc[mi][ni] = __builtin_amdgcn_mfma_f32_16x16x32_bf16(af[mi][0], bf[ni][0], acc[mi][ni], 0, 0, 0);
        acc[mi][ni] = __builtin_amdgcn_mfma_f32_16x16x32_bf16(af[mi][1], bf[ni][1], acc[mi][ni], 0, 0, 0);
      }
  }

  // coalesced epilogue: per-wave [16][36] f32 scratch (4 x 2304B = 9216B <= 16KB)
  __syncthreads();
  float* tw = (float*)(smem + wave * 2304);
  float bv4[NR];
  #pragma unroll
  for (int ni = 0; ni < NR; ++ni)
    bv4[ni] = HAS_BIAS ? bias[n0 + wc * 32 + ni * 16 + fr] : 0.0f;
  #pragma unroll
  for (int mi = 0; mi < MR; ++mi) {
    #pragma unroll
    for (int ni = 0; ni < NR; ++ni)
      #pragma unroll
      for (int r = 0; r < 4; ++r) {
        float val = acc[mi][ni][r] + bv4[ni];
        if (GELU_ACT) val = 0.5f * val * (1.0f + erff(val * 0.70710678118f));
        tw[(fg * 4 + r) * 36 + ni * 16 + fr] = val;
      }
    asm volatile("s_waitcnt lgkmcnt(0)" ::: "memory");
    __builtin_amdgcn_sched_barrier(0);
    #pragma unroll
    for (int rr = 0; rr < 2; ++rr) {
      const int row = rr * 8 + (lane >> 3);
      const int grow = m0 + wr * 32 + mi * 16 + row;
      const int gcol = n0 + wc * 32 + (lane & 7) * 4;
      f32x4 v = *(const f32x4*)&tw[row * 36 + (lane & 7) * 4];
      if (HAS_RES) v += *(const f32x4*)(res + (size_t)grow * N + gcol);
      *(f32x4*)(out + (size_t)grow * N + gcol) = v;
    }
    asm volatile("s_waitcnt lgkmcnt(0)" ::: "memory");
    __builtin_amdgcn_sched_barrier(0);
  }
}

// ---------------- 128x256 8-phase bf16 GEMM (QKV / MLP1), T2+T3+T4+T5 ----------------
// OMODE: 1 = bf16 out (coalesced), 2 = QKV split
template<int OMODE, bool HAS_BIAS, bool GELU_ACT>
__global__ __launch_bounds__(512, 1) void gemm8p2_kernel(
    const unsigned short* __restrict__ A, const unsigned short* __restrict__ Bt,
    const float* __restrict__ bias, void* __restrict__ out,
    unsigned short* __restrict__ vt, int M, int N, int K) {
  __shared__ __align__(16) char lds[98304];
  const int tid  = threadIdx.x;
  const int lane = tid & 63;
  const int wv   = tid >> 6;
  const int wm = wv >> 2, wn = wv & 3;

  const int mt = M >> 7;
  const int q8 = gridDim.x >> 3;
  const int g  = (blockIdx.x & 7) * q8 + (blockIdx.x >> 3);
  const int m0 = (g % mt) * 128, n0 = (g / mt) * 256;

  const int fr = lane & 15, fg = lane >> 4;
  const size_t K2 = (size_t)K * 2;
  const int nIter = K >> 7;

  const int csw0 = (fg * 16) ^ ((fr & 7) << 4);
  const int csw1 = (64 + fg * 16) ^ ((fr & 7) << 4);

  const int sc = (lane * 16) & 127;
  const size_t laneoff = (size_t)(lane >> 3) * K2 + (size_t)(sc ^ ((lane >> 3) << 4));
  const char* Asrc = (const char*)(A + (size_t)m0 * K) + laneoff;
  const char* Bsrc = (const char*)(Bt + (size_t)n0 * K) + laneoff;
  const int arow_wv = (wv >> 2) * 64 + (wv & 3) * 8;
  const int brow_wv = (wv >> 2) * 64 + (wv & 3) * 8;

  f32x4 acc[4][4];
  #pragma unroll
  for (int i = 0; i < 4; ++i)
    #pragma unroll
    for (int j = 0; j < 4; ++j) acc[i][j] = (f32x4){0.f, 0.f, 0.f, 0.f};

  auto stageA = [&](int b, int c, int kt) {
    GLDS16(Asrc + (size_t)(arow_wv + c * 32) * K2 + (size_t)kt * 128,
           lds + b * 49152 + c * 8192 + wv * 1024);
  };
  auto stageB = [&](int b, int j, int kt) {
    GLDS16(Bsrc + (size_t)((j & 1) * 128 + (j >> 1) * 32 + brow_wv) * K2 + (size_t)kt * 128,
           lds + b * 49152 + 16384 + j * 8192 + wv * 1024);
  };

  stageA(0, 0, 0); stageA(0, 1, 0);
  stageB(0, 0, 0); stageB(0, 1, 0); stageB(0, 2, 0); stageB(0, 3, 0);
  stageA(1, 0, 1); stageB(1, 0, 1); stageB(1, 1, 1);
  __builtin_amdgcn_sched_barrier(0);
  asm volatile("s_waitcnt vmcnt(3)" ::: "memory");
  __builtin_amdgcn_s_barrier();

  for (int i = 0; i < nIter; ++i) {
    const bool last = (i == nIter - 1);
    #pragma unroll
    for (int p = 0; p < 8; ++p) {
      const int b  = p >> 2;
      const int mh = (p >> 1) & 1;
      const int nh = p & 1;
      const char* Ab = lds + b * 49152;
      const char* Bb = Ab + 16384;
      __builtin_amdgcn_sched_barrier(0);
      short8 fa[2][2], fb[2][2];
      #pragma unroll
      for (int j = 0; j < 2; ++j) {
        const int row = mh * 64 + wm * 32 + j * 16 + fr;
        fa[j][0] = *(const short8*)(Ab + row * 128 + csw0);
        fa[j][1] = *(const short8*)(Ab + row * 128 + csw1);
      }
      #pragma unroll
      for (int n = 0; n < 2; ++n) {
        const int row = nh * 128 + (wn >> 1) * 64 + (wn & 1) * 32 + n * 16 + fr;
        fb[n][0] = *(const short8*)(Bb + row * 128 + csw0);
        fb[n][1] = *(const short8*)(Bb + row * 128 + csw1);
      }
      if (p == 0) stageA(1, 1, 2 * i + 1);
      if (p == 1) { stageB(1, 2, 2 * i + 1); stageB(1, 3, 2 * i + 1); }
      if (!last) {
        if (p == 2) stageA(0, 0, 2 * i + 2);
        if (p == 3) { stageB(0, 0, 2 * i + 2); stageB(0, 1, 2 * i + 2); }
        if (p == 4) stageA(0, 1, 2 * i + 2);
        if (p == 5) { stageB(0, 2, 2 * i + 2); stageB(0, 3, 2 * i + 2); }
        if (p == 6) stageA(1, 0, 2 * i + 3);
        if (p == 7) { stageB(1, 0, 2 * i + 3); stageB(1, 1, 2 * i + 3); }
      }
      __builtin_amdgcn_sched_barrier(0);
      __builtin_amdgcn_s_barrier();
      __builtin_amdgcn_sched_barrier(0);
      __builtin_amdgcn_s_setprio(1);
      #pragma unroll
      for (int j = 0; j < 2; ++j)
        #pragma unroll
        for (int n = 0; n < 2; ++n) {
          acc[mh * 2 + j][nh * 2 + n] = __builtin_amdgcn_mfma_f32_16x16x32_bf16(
              fa[j][0], fb[n][0], acc[mh * 2 + j][nh * 2 + n], 0, 0, 0);
          acc[mh * 2 + j][nh * 2 + n] = __builtin_amdgcn_mfma_f32_16x16x32_bf16(
              fa[j][1], fb[n][1], acc[mh * 2 + j][nh * 2 + n], 0, 0, 0);
        }
      __builtin_amdgcn_s_setprio(0);
      __builtin_amdgcn_sched_barrier(0);
      if (p == 3) {
        if (!last) asm volatile("s_waitcnt vmcnt(3)" ::: "memory");
        else       asm volatile("s_waitcnt vmcnt(0)" ::: "memory");
      }
      if (p == 7 && !last)
        asm volatile("s_waitcnt vmcnt(3)" ::: "memory");
      __builtin_amdgcn_s_barrier();
    }
  }

  if (OMODE == 1) {
    unsigned short* tw = (unsigned short*)(lds + wv * 2176);
    float bv4[4];
    #pragma unroll
    for (int ni = 0; ni < 4; ++ni)
      bv4[ni] = HAS_BIAS ? bias[n0 + wn * 64 + ni * 16 + fr] : 0.0f;
    #pragma unroll
    for (int mi = 0; mi < 4; ++mi) {
      #pragma unroll
      for (int ni = 0; ni < 4; ++ni)
        #pragma unroll
        for (int r = 0; r < 4; ++r) {
          float val = acc[mi][ni][r] + bv4[ni];
          if (GELU_ACT) val = 0.5f * val * (1.0f + erff(val * 0.70710678118f));
          tw[(fg * 4 + r) * 68 + ni * 16 + fr] = f2bf(val);
        }
      asm volatile("s_waitcnt lgkmcnt(0)" ::: "memory");
      __builtin_amdgcn_sched_barrier(0);
      #pragma unroll
      for (int rr = 0; rr < 4; ++rr) {
        const int row = rr * 4 + (lane >> 4);
        const int grow = m0 + wm * 64 + mi * 16 + row;
        const int gcol = n0 + wn * 64 + (lane & 15) * 4;
        ushort4 v = *(const ushort4*)&tw[row * 68 + (lane & 15) * 4];
        *(ushort4*)((unsigned short*)out + (size_t)grow * N + gcol) = v;
      }
      asm volatile("s_waitcnt lgkmcnt(0)" ::: "memory");
      __builtin_amdgcn_sched_barrier(0);
    }
  } else {
    #pragma unroll
    for (int mi = 0; mi < 4; ++mi) {
      #pragma unroll
      for (int ni = 0; ni < 4; ++ni) {
        const int col = n0 + wn * 64 + ni * 16 + fr;
        float bv = HAS_BIAS ? bias[col] : 0.0f;
        const int rbase = m0 + wm * 64 + mi * 16 + fg * 4;
        float vals[4];
        #pragma unroll
        for (int r = 0; r < 4; ++r) vals[r] = acc[mi][ni][r] + bv;
        if (col < 2 * E_DIM) {
          #pragma unroll
          for (int r = 0; r < 4; ++r)
            ((unsigned short*)out)[(size_t)(rbase + r) * 2 * E_DIM + col] = f2bf(vals[r]);
        } else {
          const int c2 = col - 2 * E_DIM;
          const int hh = c2 >> 6, d = c2 & 63;
          const int bb = rbase >> 10, t0 = rbase & (T_SEQ - 1);
          ushort4 o;
          o.x = f2bf(vals[0]); o.y = f2bf(vals[1]);
          o.z = f2bf(vals[2]); o.w = f2bf(vals[3]);
          *(ushort4*)(vt + ((size_t)(bb * H_HEADS + hh) * D_HEAD + d) * T_SEQ + t0) = o;
        }
      }
    }
  }
}

// ---------------- 256x256 8-phase bf16 GEMM (LM head), XCD-grouped, direct stores ----------------
__global__ __launch_bounds__(512, 1) void gemm8p_kernel(
    const unsigned short* __restrict__ A, const unsigned short* __restrict__ Bt,
    const float* __restrict__ bias, float* __restrict__ out, int M, int N, int K) {
  __shared__ __align__(16) char lds[131072];
  const int tid  = threadIdx.x;
  const int lane = tid & 63;
  const int wv   = tid >> 6;
  const int wm = wv >> 2, wn = wv & 3;

  const int mt = M >> 8;
  const int q8 = gridDim.x >> 3;
  const int g  = (blockIdx.x & 7) * q8 + (blockIdx.x >> 3);
  const int m0 = (g % mt) * 256, n0 = (g / mt) * 256;

  const int fr = lane & 15, fg = lane >> 4;
  const size_t K2 = (size_t)K * 2;
  const int nIter = K >> 7;

  const int csw0 = (fg * 16) ^ ((fr & 7) << 4);
  const int csw1 = (64 + fg * 16) ^ ((fr & 7) << 4);

  const int sc = (lane * 16) & 127;
  const size_t laneoff = (size_t)(lane >> 3) * K2 + (size_t)(sc ^ ((lane >> 3) << 4));
  const char* Asrc = (const char*)(A + (size_t)m0 * K) + (size_t)(wv * 8) * K2 + laneoff;
  const char* Bsrc = (const char*)(Bt + (size_t)n0 * K) + laneoff;

  f32x4 acc[8][4];
  #pragma unroll
  for (int i = 0; i < 8; ++i)
    #pragma unroll
    for (int j = 0; j < 4; ++j) acc[i][j] = (f32x4){0.f, 0.f, 0.f, 0.f};

  auto stageA = [&](int b, int q, int kt) {
    GLDS16(Asrc + (size_t)(q * 64) * K2 + (size_t)kt * 128,
           lds + b * 65536 + q * 8192 + wv * 1024);
  };
  auto stageB = [&](int b, int j, int o, int kt) {
    const int gw = j * 64 + wv * 8;
    const int rw = ((gw >> 5) << 6) + (gw & 31) + o * 32;
    GLDS16(Bsrc + (size_t)rw * K2 + (size_t)kt * 128,
           lds + b * 65536 + 32768 + rw * 128);
  };

  stageA(0, 0, 0); stageA(0, 2, 0);
  stageB(0, 0, 0, 0); stageB(0, 1, 0, 0);
  stageA(0, 1, 0); stageA(0, 3, 0);
  stageB(0, 0, 1, 0); stageB(0, 1, 1, 0);
  stageA(1, 0, 1); stageA(1, 2, 1);
  stageB(1, 0, 0, 1); stageB(1, 1, 0, 1);
  __builtin_amdgcn_sched_barrier(0);
  asm volatile("s_waitcnt vmcnt(4)" ::: "memory");
  __builtin_amdgcn_s_barrier();

  for (int i = 0; i < nIter; ++i) {
    const bool last = (i == nIter - 1);
    #pragma unroll
    for (int p = 0; p < 8; ++p) {
      const int b  = p >> 2;
      const int mh = (p & 3) >> 1;
      const int nh = p & 1;
      const char* Ab = lds + b * 65536;
      const char* Bb = Ab + 32768;
      __builtin_amdgcn_sched_barrier(0);
      short8 fa[4][2], fb[2][2];
      #pragma unroll
      for (int j = 0; j < 4; ++j) {
        const int row = wm * 128 + mh * 64 + j * 16 + fr;
        fa[j][0] = *(const short8*)(Ab + row * 128 + csw0);
        fa[j][1] = *(const short8*)(Ab + row * 128 + csw1);
      }
      #pragma unroll
      for (int n = 0; n < 2; ++n) {
        const int row = wn * 64 + nh * 32 + n * 16 + fr;
        fb[n][0] = *(const short8*)(Bb + row * 128 + csw0);
        fb[n][1] = *(const short8*)(Bb + row * 128 + csw1);
      }
      if (p == 0) { stageA(1, 1, 2 * i + 1); stageA(1, 3, 2 * i + 1); }
      if (p == 1) { stageB(1, 0, 1, 2 * i + 1); stageB(1, 1, 1, 2 * i + 1); }
      if (!last) {
        if (p == 2) { stageA(0, 0, 2 * i + 2); stageA(0, 2, 2 * i + 2); }
        if (p == 3) { stageB(0, 0, 0, 2 * i + 2); stageB(0, 1, 0, 2 * i + 2); }
        if (p == 4) { stageA(0, 1, 2 * i + 2); stageA(0, 3, 2 * i + 2); }
        if (p == 5) { stageB(0, 0, 1, 2 * i + 2); stageB(0, 1, 1, 2 * i + 2); }
        if (p == 6) { stageA(1, 0, 2 * i + 3); stageA(1, 2, 2 * i + 3); }
        if (p == 7) { stageB(1, 0, 0, 2 * i + 3); stageB(1, 1, 0, 2 * i + 3); }
      }
      __builtin_amdgcn_sched_barrier(0);
      __builtin_amdgcn_s_barrier();
      __builtin_amdgcn_sched_barrier(0);
      __builtin_amdgcn_s_setprio(1);
      #pragma unroll
      for (int j = 0; j < 4; ++j)
        #pragma unroll
        for (int n = 0; n < 2; ++n) {
          acc[mh * 4 + j][nh * 2 + n] = __builtin_amdgcn_mfma_f32_16x16x32_bf16(
              fa[j][0], fb[n][0], acc[mh * 4 + j][nh * 2 + n], 0, 0, 0);
          acc[mh * 4 + j][nh * 2 + n] = __builtin_amdgcn_mfma_f32_16x16x32_bf16(
              fa[j][1], fb[n][1], acc[mh * 4 + j][nh * 2 + n], 0, 0, 0);
        }
      __builtin_amdgcn_s_setprio(0);
      __builtin_amdgcn_sched_barrier(0);
      if (p == 3) {
        if (!last) asm volatile("s_waitcnt vmcnt(4)" ::: "memory");
        else       asm volatile("s_waitcnt vmcnt(0)" ::: "memory");
      }
      if (p == 7 && !last)
        asm volatile("s_waitcnt vmcnt(4)" ::: "memory");
      __builtin_amdgcn_s_barrier();
    }
  }

  #pragma unroll
  for (int mi = 0; mi < 8; ++mi) {
    #pragma unroll
    for (int ni = 0; ni < 4; ++ni) {
      const int col = n0 + wn * 64 + ni * 16 + fr;
      const float bv = bias[col];
      #pragma unroll
      for (int r = 0; r < 4; ++r) {
        const int row = m0 + wm * 128 + mi * 16 + fg * 4 + r;
        out[(size_t)row * N + col] = acc[mi][ni][r] + bv;
      }
    }
  }
}

extern "C" void kernel_launch(void* const* d_in, const int* in_sizes, int n_in,
                              void* d_out, int out_size, void* d_ws, size_t ws_size,
                              hipStream_t stream) {
  const int*   idx   = (const int*)  d_in[0];
  const float* tok_w = (const float*)d_in[1];
  const float* pos_w = (const float*)d_in[2];
  const float* ln1_g = (const float*)d_in[3];
  const float* ln1_b = (const float*)d_in[4];
  const float* wq    = (const float*)d_in[5];
  const float* wk    = (const float*)d_in[6];
  const float* wv    = (const float*)d_in[7];
  const float* wp    = (const float*)d_in[8];
  const float* bp    = (const float*)d_in[9];
  const float* ln2_g = (const float*)d_in[10];
  const float* ln2_b = (const float*)d_in[11];
  const float* w1    = (const float*)d_in[12];
  const float* b1    = (const float*)d_in[13];
  const float* w2    = (const float*)d_in[14];
  const float* b2    = (const float*)d_in[15];
  const float* lnf_g = (const float*)d_in[16];
  const float* lnf_b = (const float*)d_in[17];
  const float* wlm   = (const float*)d_in[18];
  const float* blm   = (const float*)d_in[19];

  const int M = B_BATCH * T_SEQ;  // 2048
  const size_t EE = (size_t)E_DIM * E_DIM;
  const size_t EF = (size_t)E_DIM * F_DIM;
  char* p = (char*)d_ws;
  float* x            = (float*)p;          p += (size_t)M * E_DIM * 4;
  unsigned short* hb  = (unsigned short*)p; p += (size_t)M * E_DIM * 2;
  unsigned short* qkb = (unsigned short*)p; p += (size_t)M * 2 * E_DIM * 2;
  unsigned short* vtb = (unsigned short*)p; p += (size_t)M * E_DIM * 2;
  unsigned short* yb  = (unsigned short*)p; p += (size_t)M * E_DIM * 2;
  unsigned short* tb  = (unsigned short*)p; p += (size_t)M * F_DIM * 2;
  unsigned short* wtb = (unsigned short*)p; p += (size_t)V_VOCAB * E_DIM * 2;

  embed_kernel<<<M * E_DIM / 4 / 256, 256, 0, stream>>>(idx, tok_w, pos_w, x);

  for (int l = 0; l < L_LAYERS; ++l) {
    wtrans6ln_kernel<<<5120, 256, 0, stream>>>(
        wq + l * EE, wk + l * EE, wv + l * EE, wp + l * EE,
        w1 + l * EF, w2 + l * EF,
        ln1_g + (size_t)l * E_DIM, ln1_b + (size_t)l * E_DIM, x, wtb, hb);
    gemm8p2_kernel<2, false, false>
        <<<(M / 128) * (3 * E_DIM / 256), 512, 0, stream>>>(
        hb, wtb, nullptr, qkb, vtb, M, 3 * E_DIM, E_DIM);
    attn_mfma_kernel<<<dim3(16, B_BATCH * H_HEADS), 512, 0, stream>>>(qkb, vtb, yb);
    gemm_bt_kernel<true, false, true>
        <<<(M / 64) * (E_DIM / 64), 256, 0, stream>>>(
        yb, wtb + 3 * EE, bp + (size_t)l * E_DIM, x, x, M, E_DIM, E_DIM);
    ln_kernel<<<M, 256, 0, stream>>>(x, ln2_g + (size_t)l * E_DIM, ln2_b + (size_t)l * E_DIM, hb);
    gemm8p2_kernel<1, true, true>
        <<<(M / 128) * (F_DIM / 256), 512, 0, stream>>>(
        hb, wtb + 4 * EE, b1 + (size_t)l * F_DIM, tb, nullptr, M, F_DIM, E_DIM);
    gemm_bt_kernel<true, false, true>
        <<<(M / 64) * (E_DIM / 64), 256, 0, stream>>>(
        tb, wtb + 4 * EE + EF, b2 + (size_t)l * E_DIM, x, x, M, E_DIM, F_DIM);
  }
  wtransv_ln_kernel<<<10048, 256, 0, stream>>>(wlm, lnf_g, lnf_b, x, wtb, hb);
  gemm8p_kernel<<<(M / 256) * (V_VOCAB / 256), 512, 0, stream>>>(
      hb, wtb, blm, (float*)d_out, M, V_VOCAB, E_DIM);
}

// Round 15
// 1177.932 us; speedup vs baseline: 1.1082x; 1.0122x over previous
//
#include <hip/hip_runtime.h>

#define T_SEQ   1024
#define E_DIM   1024
#define H_HEADS 16
#define D_HEAD  64
#define L_LAYERS 6
#define B_BATCH 2
#define F_DIM   4096
#define V_VOCAB 32000

typedef float f32x4 __attribute__((ext_vector_type(4)));
typedef short short8 __attribute__((ext_vector_type(8)));

__device__ __forceinline__ unsigned short f2bf(float f) {
  union { float f; unsigned int u; } v; v.f = f;
  unsigned int r = v.u + 0x7fffu + ((v.u >> 16) & 1u);  // RNE
  return (unsigned short)(r >> 16);
}

// async global->LDS, 16B per lane; lds dest = wave-uniform base + lane*16
#define GLDS16(gp, lp) __builtin_amdgcn_global_load_lds( \
    (const __attribute__((address_space(1))) void*)(gp), \
    (__attribute__((address_space(3))) void*)(lp), 16, 0, 0)

// ---------------- embedding: x = tok_w[idx] + pos_w ----------------
__global__ void embed_kernel(const int* __restrict__ idx, const float* __restrict__ tok,
                             const float* __restrict__ pos, float* __restrict__ x) {
  int i = blockIdx.x * 256 + threadIdx.x;
  int bt = i >> 8;
  int e4 = i & 255;
  int t  = bt & (T_SEQ - 1);
  int tokid = idx[bt];
  f32x4 a = *(const f32x4*)(tok + (size_t)tokid * E_DIM + e4 * 4);
  f32x4 p = *(const f32x4*)(pos + (size_t)t * E_DIM + e4 * 4);
  *(f32x4*)(x + (size_t)bt * E_DIM + e4 * 4) = a + p;
}

// ---------------- layernorm body (f32 in, bf16 out), 256 threads ----------------
__device__ __forceinline__ void ln_body(const float* __restrict__ x,
    const float* __restrict__ g, const float* __restrict__ b,
    unsigned short* __restrict__ out, int row) {
  int tid = threadIdx.x;
  const float* xr = x + (size_t)row * E_DIM;
  f32x4 v = *(const f32x4*)(xr + tid * 4);
  float s  = v[0] + v[1] + v[2] + v[3];
  float s2 = v[0]*v[0] + v[1]*v[1] + v[2]*v[2] + v[3]*v[3];
  #pragma unroll
  for (int off = 32; off > 0; off >>= 1) {
    s  += __shfl_xor(s,  off);
    s2 += __shfl_xor(s2, off);
  }
  __shared__ float red[2][4];
  int wave = tid >> 6;
  if ((tid & 63) == 0) { red[0][wave] = s; red[1][wave] = s2; }
  __syncthreads();
  s  = red[0][0] + red[0][1] + red[0][2] + red[0][3];
  s2 = red[1][0] + red[1][1] + red[1][2] + red[1][3];
  float mean = s * (1.0f / E_DIM);
  float var  = s2 * (1.0f / E_DIM) - mean * mean;
  float rstd = rsqrtf(var + 1e-5f);
  f32x4 gv = *(const f32x4*)(g + tid * 4);
  f32x4 bv = *(const f32x4*)(b + tid * 4);
  ushort4 o;
  o.x = f2bf((v[0] - mean) * rstd * gv[0] + bv[0]);
  o.y = f2bf((v[1] - mean) * rstd * gv[1] + bv[1]);
  o.z = f2bf((v[2] - mean) * rstd * gv[2] + bv[2]);
  o.w = f2bf((v[3] - mean) * rstd * gv[3] + bv[3]);
  *(ushort4*)(out + (size_t)row * E_DIM + tid * 4) = o;
}

__global__ void ln_kernel(const float* __restrict__ x, const float* __restrict__ g,
                          const float* __restrict__ b, unsigned short* __restrict__ out) {
  ln_body(x, g, b, out, blockIdx.x);
}

// ---------------- weight transpose+convert: W f32 [K][N] -> Wt bf16 [N][K] ----------------
__device__ __forceinline__ void wtrans_body(const float* __restrict__ W,
    unsigned short* __restrict__ Wt, int K, int N, int bx, int by) {
  __shared__ float tile[64][65];
  const int n0 = bx * 64, k0 = by * 64;
  const int tr  = threadIdx.x >> 4;
  const int tc4 = (threadIdx.x & 15) * 4;
  #pragma unroll
  for (int p = 0; p < 4; ++p) {
    f32x4 v = *(const f32x4*)(W + (size_t)(k0 + p * 16 + tr) * N + n0 + tc4);
    tile[p * 16 + tr][tc4 + 0] = v[0];
    tile[p * 16 + tr][tc4 + 1] = v[1];
    tile[p * 16 + tr][tc4 + 2] = v[2];
    tile[p * 16 + tr][tc4 + 3] = v[3];
  }
  __syncthreads();
  #pragma unroll
  for (int p = 0; p < 4; ++p) {
    int n = p * 16 + tr;
    ushort4 o;
    o.x = f2bf(tile[tc4 + 0][n]);
    o.y = f2bf(tile[tc4 + 1][n]);
    o.z = f2bf(tile[tc4 + 2][n]);
    o.w = f2bf(tile[tc4 + 3][n]);
    *(ushort4*)(Wt + (size_t)(n0 + n) * K + k0 + tc4) = o;
  }
}

// layer weights (q,k,v,p,w1,w2) + ln1 in one launch; grid = 3072 + 2048
__global__ __launch_bounds__(256) void wtrans6ln_kernel(const float* __restrict__ wq,
    const float* __restrict__ wk, const float* __restrict__ wv, const float* __restrict__ wp,
    const float* __restrict__ w1, const float* __restrict__ w2,
    const float* __restrict__ lng, const float* __restrict__ lnb,
    const float* __restrict__ x, unsigned short* __restrict__ wtb,
    unsigned short* __restrict__ hb) {
  const size_t EE = (size_t)E_DIM * E_DIM;
  const size_t EF = (size_t)E_DIM * F_DIM;
  const int id = blockIdx.x;
  if (id < 1024) {
    const int z = id >> 8, r = id & 255;
    const float* W = z == 0 ? wq : (z == 1 ? wk : (z == 2 ? wv : wp));
    wtrans_body(W, wtb + z * EE, E_DIM, E_DIM, r & 15, r >> 4);
  } else if (id < 2048) {
    const int r = id - 1024;
    wtrans_body(w1, wtb + 4 * EE, E_DIM, F_DIM, r & 63, r >> 6);
  } else if (id < 3072) {
    const int r = id - 2048;
    wtrans_body(w2, wtb + 4 * EE + EF, F_DIM, E_DIM, r & 15, r >> 4);
  } else {
    ln_body(x, lng, lnb, hb, id - 3072);
  }
}

// LM weight transpose + final layernorm; grid = 8000 + 2048
__global__ __launch_bounds__(256) void wtransv_ln_kernel(const float* __restrict__ wlm,
    const float* __restrict__ lng, const float* __restrict__ lnb,
    const float* __restrict__ x, unsigned short* __restrict__ wtb,
    unsigned short* __restrict__ hb) {
  const int id = blockIdx.x;
  if (id < 8000) wtrans_body(wlm, wtb, E_DIM, V_VOCAB, id % 500, id / 500);
  else           ln_body(x, lng, lnb, hb, id - 8000);
}

// ---------------- MFMA flash attention, split-key, all-waves-busy ----------------
__global__ __launch_bounds__(512) void attn_mfma_kernel(
    const unsigned short* __restrict__ qk, const unsigned short* __restrict__ vt,
    unsigned short* __restrict__ y) {
  __shared__ __align__(16) char smem[2 * 16384 + 8 * 1280 + 512];
  const int tid  = threadIdx.x;
  const int lane = tid & 63;
  const int wave = tid >> 6;
  const int wl = wave & 3;
  const int g  = wave >> 2;
  const int qx = blockIdx.x;
  const int h  = blockIdx.y & (H_HEADS - 1);
  const int b  = blockIdx.y >> 4;
  const int qt = b ? (15 - qx) : qx;
  const int r0 = qt * 64 + wl * 16;
  const size_t RS = 2 * E_DIM;
  const unsigned short* q  = qk + (size_t)b * T_SEQ * RS + (size_t)h * D_HEAD;
  const unsigned short* k  = q + E_DIM;
  const unsigned short* vb = vt + (size_t)(b * H_HEADS + h) * D_HEAD * T_SEQ;
  const size_t ybase = (size_t)b * T_SEQ * E_DIM + (size_t)h * D_HEAD;
  const int fr = lane & 15, fg = lane >> 4;
  const int srow = lane >> 3;
  const int ssw  = ((lane & 7) * 16) ^ (srow << 4);
  char* pb = smem + 32768 + wave * 1280;
  float* mlb = (float*)(smem + 32768 + 10240);

  short8 aq[2];
  #pragma unroll
  for (int c = 0; c < 2; ++c)
    aq[c] = *(const short8*)(q + (size_t)(r0 + fr) * RS + c * 32 + fg * 8);

  f32x4 oacc[4];
  #pragma unroll
  for (int cg = 0; cg < 4; ++cg) oacc[cg] = (f32x4){0.f, 0.f, 0.f, 0.f};
  float m_ = -1e30f, l_ = 0.0f;

  auto stage = [&](int t) {
    const int j0 = t * 64;
    char* Kd = smem + (t & 1) * 16384;
    GLDS16((const char*)k  + (size_t)(j0 + wave * 8 + srow) * RS * 2 + ssw,
           Kd + wave * 1024);
    GLDS16((const char*)vb + ((size_t)(wave * 8 + srow) * T_SEQ + j0) * 2 + ssw,
           Kd + 8192 + wave * 1024);
  };

  stage(0);
  for (int t = 0; t <= qt; ++t) {
    __builtin_amdgcn_sched_barrier(0);
    __builtin_amdgcn_s_barrier();
    if (t < qt) stage(t + 1);
    __builtin_amdgcn_sched_barrier(0);
    if (t < qt) asm volatile("s_waitcnt vmcnt(2)" ::: "memory");
    else        asm volatile("s_waitcnt vmcnt(0)" ::: "memory");
    __builtin_amdgcn_sched_barrier(0);
    __builtin_amdgcn_s_barrier();
    __builtin_amdgcn_sched_barrier(0);
    const char* Kl = smem + (t & 1) * 16384;
    const char* Vl = Kl + 8192;
    const int j0 = t * 64;
    if (!(t == qt && g == 1 && wl < 2)) {
      f32x4 st[2];
      #pragma unroll
      for (int cc = 0; cc < 2; ++cc) {
        const int kloc = g * 32 + cc * 16 + fr;
        const char* kb = Kl + kloc * 128;
        const int sw = (kloc & 7) << 4;
        short8 ka0 = *(const short8*)(kb + ((fg * 16) ^ sw));
        short8 ka1 = *(const short8*)(kb + ((64 + fg * 16) ^ sw));
        f32x4 z = (f32x4){0.f, 0.f, 0.f, 0.f};
        z = __builtin_amdgcn_mfma_f32_16x16x32_bf16(ka0, aq[0], z, 0, 0, 0);
        z = __builtin_amdgcn_mfma_f32_16x16x32_bf16(ka1, aq[1], z, 0, 0, 0);
        st[cc] = z;
      }
      const int qg = r0 + fr;
      float pv[2][4];
      float mx = -1e30f;
      #pragma unroll
      for (int cc = 0; cc < 2; ++cc)
        #pragma unroll
        for (int r = 0; r < 4; ++r) {
          const int kj = j0 + g * 32 + cc * 16 + fg * 4 + r;
          float val = (kj <= qg) ? st[cc][r] * 0.125f : -1e30f;
          pv[cc][r] = val;
          mx = fmaxf(mx, val);
        }
      mx = fmaxf(mx, __shfl_xor(mx, 16));
      mx = fmaxf(mx, __shfl_xor(mx, 32));
      const float mn = fmaxf(m_, mx);
      const float cfs = __expf(m_ - mn);
      float ls = 0.0f;
      #pragma unroll
      for (int cc = 0; cc < 2; ++cc) {
        ushort4 o;
        float e0 = pv[cc][0] > -1e29f ? __expf(pv[cc][0] - mn) : 0.0f;
        float e1 = pv[cc][1] > -1e29f ? __expf(pv[cc][1] - mn) : 0.0f;
        float e2 = pv[cc][2] > -1e29f ? __expf(pv[cc][2] - mn) : 0.0f;
        float e3 = pv[cc][3] > -1e29f ? __expf(pv[cc][3] - mn) : 0.0f;
        ls += (e0 + e1) + (e2 + e3);
        o.x = f2bf(e0); o.y = f2bf(e1); o.z = f2bf(e2); o.w = f2bf(e3);
        *(ushort4*)(pb + fr * 80 + cc * 32 + fg * 8) = o;
      }
      ls += __shfl_xor(ls, 16);
      ls += __shfl_xor(ls, 32);
      l_ = l_ * cfs + ls;
      m_ = mn;
      float cfO[4];
      #pragma unroll
      for (int r = 0; r < 4; ++r) cfO[r] = __shfl(cfs, (lane & 48) | (fg * 4 + r));
      asm volatile("s_waitcnt lgkmcnt(0)" ::: "memory");
      __builtin_amdgcn_sched_barrier(0);
      short8 pa = *(const short8*)(pb + fr * 80 + fg * 16);
      __builtin_amdgcn_s_setprio(1);
      #pragma unroll
      for (int cg = 0; cg < 4; ++cg) {
        const int d = cg * 16 + fr;
        short8 bv = *(const short8*)(Vl + d * 128 + ((g * 64 + fg * 16) ^ ((d & 7) << 4)));
        #pragma unroll
        for (int r = 0; r < 4; ++r) oacc[cg][r] *= cfO[r];
        oacc[cg] = __builtin_amdgcn_mfma_f32_16x16x32_bf16(pa, bv, oacc[cg], 0, 0, 0);
      }
      __builtin_amdgcn_s_setprio(0);
    }
  }
  __syncthreads();
  float* obuf = (float*)smem;
  if (g == 1) {
    #pragma unroll
    for (int cg = 0; cg < 4; ++cg)
      #pragma unroll
      for (int r = 0; r < 4; ++r)
        obuf[wl * 1024 + (fg * 4 + r) * 64 + cg * 16 + fr] = oacc[cg][r];
    if (fg == 0) { mlb[(wl * 16 + fr) * 2] = m_; mlb[(wl * 16 + fr) * 2 + 1] = l_; }
  }
  __syncthreads();
  if (g == 0) {
    const float m1 = mlb[(wl * 16 + fr) * 2];
    const float l1 = mlb[(wl * 16 + fr) * 2 + 1];
    const float m  = fmaxf(m_, m1);
    const float c0 = __expf(m_ - m), c1 = __expf(m1 - m);
    const float li = 1.0f / (l_ * c0 + l1 * c1);
    float c0O[4], c1O[4], liO[4];
    #pragma unroll
    for (int r = 0; r < 4; ++r) {
      const int src = (lane & 48) | (fg * 4 + r);
      c0O[r] = __shfl(c0, src); c1O[r] = __shfl(c1, src); liO[r] = __shfl(li, src);
    }
    #pragma unroll
    for (int cg = 0; cg < 4; ++cg)
      #pragma unroll
      for (int r = 0; r < 4; ++r) {
        const float o1 = obuf[wl * 1024 + (fg * 4 + r) * 64 + cg * 16 + fr];
        const float val = (oacc[cg][r] * c0O[r] + o1 * c1O[r]) * liO[r];
        y[ybase + (size_t)(r0 + fg * 4 + r) * E_DIM + cg * 16 + fr] = f2bf(val);
      }
  }
}

// ---------------- 64x64 bf16 GEMM, BK=64, 2-barrier, 2 blocks/CU ----------------
// OMODE 0: f32 out + res (proj / MLP2).  OMODE 2: QKV split (Q/K -> qk stride 2E
// via scratch-transposed ushort4 stores; V -> vt[b,h,d][t] direct ushort4).
template<int OMODE, bool HAS_BIAS, bool GELU_ACT, bool HAS_RES>
__global__ __launch_bounds__(256) void gemm_bt_kernel(
    const unsigned short* __restrict__ A, const unsigned short* __restrict__ Bt,
    const float* __restrict__ bias, const float* __restrict__ res,
    void* __restrict__ out, unsigned short* __restrict__ vt, int M, int N, int K) {
  constexpr int BM = 64, BN = 64, BK = 64;
  constexpr int MR = 2, NR = 2;
  __shared__ __align__(16) char smem[(BM + BN) * BK * 2];   // As | Bs, epilogue scratch
  unsigned short* As = (unsigned short*)smem;
  unsigned short* Bs = (unsigned short*)(smem + BM * BK * 2);
  const int tid  = threadIdx.x;
  const int lane = tid & 63;
  const int wave = tid >> 6;
  const int wr = wave >> 1, wc = wave & 1;

  const int mt = M / BM;
  const int q8 = gridDim.x >> 3;
  const int g  = (blockIdx.x & 7) * q8 + (blockIdx.x >> 3);
  const int m0 = (g % mt) * BM, n0 = (g / mt) * BN;

  const int fr = lane & 15, fg = lane >> 4;
  const int lrow = lane >> 3;
  const int scol = ((lane & 7) * 16) ^ (lrow << 4);
  const size_t K2 = (size_t)K * 2;
  const char* aG = (const char*)A  + (size_t)(m0 + wave * 8 + lrow) * K2 + scol;
  const char* bG = (const char*)Bt + (size_t)(n0 + wave * 8 + lrow) * K2 + scol;

  f32x4 acc[MR][NR];
  #pragma unroll
  for (int mi = 0; mi < MR; ++mi)
    #pragma unroll
    for (int ni = 0; ni < NR; ++ni) acc[mi][ni] = (f32x4){0.f, 0.f, 0.f, 0.f};

  for (int k0 = 0; k0 < K; k0 += BK) {
    __syncthreads();
    #pragma unroll
    for (int i = 0; i < 2; ++i)
      GLDS16(aG + (size_t)i * 32 * K2 + (size_t)k0 * 2, (char*)As + wave * 1024 + i * 4096);
    #pragma unroll
    for (int i = 0; i < 2; ++i)
      GLDS16(bG + (size_t)i * 32 * K2 + (size_t)k0 * 2, (char*)Bs + wave * 1024 + i * 4096);
    __syncthreads();

    short8 af[MR][2], bf[NR][2];
    #pragma unroll
    for (int mi = 0; mi < MR; ++mi) {
      const int row = wr * 32 + mi * 16 + fr;
      #pragma unroll
      for (int kh = 0; kh < 2; ++kh)
        af[mi][kh] = *(const short8*)((const char*)As + row * 128 +
                       ((kh * 64 + fg * 16) ^ ((row & 7) << 4)));
    }
    #pragma unroll
    for (int ni = 0; ni < NR; ++ni) {
      const int row = wc * 32 + ni * 16 + fr;
      #pragma unroll
      for (int kh = 0; kh < 2; ++kh)
        bf[ni][kh] = *(const short8*)((const char*)Bs + row * 128 +
                       ((kh * 64 + fg * 16) ^ ((row & 7) << 4)));
    }
    #pragma unroll
    for (int mi = 0; mi < MR; ++mi)
      #pragma unroll
      for (int ni = 0; ni < NR; ++ni) {
        acc[mi][ni] = __builtin_amdgcn_mfma_f32_16x16x32_bf16(af[mi][0], bf[ni][0], acc[mi][ni], 0, 0, 0);
        acc[mi][ni] = __builtin_amdgcn_mfma_f32_16x16x32_bf16(af[mi][1], bf[ni][1], acc[mi][ni], 0, 0, 0);
      }
  }

  if (OMODE == 0) {
    // coalesced epilogue: per-wave [16][36] f32 scratch (4 x 2304B = 9216B <= 16KB)
    __syncthreads();
    float* tw = (float*)(smem + wave * 2304);
    float bv4[NR];
    #pragma unroll
    for (int ni = 0; ni < NR; ++ni)
      bv4[ni] = HAS_BIAS ? bias[n0 + wc * 32 + ni * 16 + fr] : 0.0f;
    #pragma unroll
    for (int mi = 0; mi < MR; ++mi) {
      #pragma unroll
      for (int ni = 0; ni < NR; ++ni)
        #pragma unroll
        for (int r = 0; r < 4; ++r) {
          float val = acc[mi][ni][r] + bv4[ni];
          if (GELU_ACT) val = 0.5f * val * (1.0f + erff(val * 0.70710678118f));
          tw[(fg * 4 + r) * 36 + ni * 16 + fr] = val;
        }
      asm volatile("s_waitcnt lgkmcnt(0)" ::: "memory");
      __builtin_amdgcn_sched_barrier(0);
      #pragma unroll
      for (int rr = 0; rr < 2; ++rr) {
        const int row = rr * 8 + (lane >> 3);
        const int grow = m0 + wr * 32 + mi * 16 + row;
        const int gcol = n0 + wc * 32 + (lane & 7) * 4;
        f32x4 v = *(const f32x4*)&tw[row * 36 + (lane & 7) * 4];
        if (HAS_RES) v += *(const f32x4*)(res + (size_t)grow * N + gcol);
        *(f32x4*)((float*)out + (size_t)grow * N + gcol) = v;
      }
      asm volatile("s_waitcnt lgkmcnt(0)" ::: "memory");
      __builtin_amdgcn_sched_barrier(0);
    }
  } else {
    // QKV split; n0 is a multiple of 64 so the whole block is Q/K or V.
    if (n0 < 2 * E_DIM) {
      // Q/K: scratch-transposed bf16, ushort4 stores (64B rows) to stride-2E buf
      __syncthreads();
      unsigned short* tw = (unsigned short*)(smem + wave * 2304);
      #pragma unroll
      for (int mi = 0; mi < MR; ++mi) {
        #pragma unroll
        for (int ni = 0; ni < NR; ++ni)
          #pragma unroll
          for (int r = 0; r < 4; ++r)
            tw[(fg * 4 + r) * 36 + ni * 16 + fr] = f2bf(acc[mi][ni][r]);
        asm volatile("s_waitcnt lgkmcnt(0)" ::: "memory");
        __builtin_amdgcn_sched_barrier(0);
        #pragma unroll
        for (int rr = 0; rr < 2; ++rr) {
          const int row = rr * 8 + (lane >> 3);
          const int grow = m0 + wr * 32 + mi * 16 + row;
          const int gcol = n0 + wc * 32 + (lane & 7) * 4;
          ushort4 v = *(const ushort4*)&tw[row * 36 + (lane & 7) * 4];
          *(ushort4*)((unsigned short*)out + (size_t)grow * 2 * E_DIM + gcol) = v;
        }
        asm volatile("s_waitcnt lgkmcnt(0)" ::: "memory");
        __builtin_amdgcn_sched_barrier(0);
      }
    } else {
      // V: vt[(b*16+h)*64+d][t], 4 consecutive t per store
      #pragma unroll
      for (int mi = 0; mi < MR; ++mi)
        #pragma unroll
        for (int ni = 0; ni < NR; ++ni) {
          const int col = n0 + wc * 32 + ni * 16 + fr;
          const int c2 = col - 2 * E_DIM;
          const int hh = c2 >> 6, d = c2 & 63;
          const int rbase = m0 + wr * 32 + mi * 16 + fg * 4;
          const int bb = rbase >> 10, t0 = rbase & (T_SEQ - 1);
          ushort4 o;
          o.x = f2bf(acc[mi][ni][0]); o.y = f2bf(acc[mi][ni][1]);
          o.z = f2bf(acc[mi][ni][2]); o.w = f2bf(acc[mi][ni][3]);
          *(ushort4*)(vt + ((size_t)(bb * H_HEADS + hh) * D_HEAD + d) * T_SEQ + t0) = o;
        }
    }
  }
}

// ---------------- 128x256 8-phase bf16 GEMM (MLP1), T2+T3+T4+T5 ----------------
template<bool HAS_BIAS, bool GELU_ACT>
__global__ __launch_bounds__(512, 1) void gemm8p2_kernel(
    const unsigned short* __restrict__ A, const unsigned short* __restrict__ Bt,
    const float* __restrict__ bias, unsigned short* __restrict__ out,
    int M, int N, int K) {
  __shared__ __align__(16) char lds[98304];
  const int tid  = threadIdx.x;
  const int lane = tid & 63;
  const int wv   = tid >> 6;
  const int wm = wv >> 2, wn = wv & 3;

  const int mt = M >> 7;
  const int q8 = gridDim.x >> 3;
  const int g  = (blockIdx.x & 7) * q8 + (blockIdx.x >> 3);
  const int m0 = (g % mt) * 128, n0 = (g / mt) * 256;

  const int fr = lane & 15, fg = lane >> 4;
  const size_t K2 = (size_t)K * 2;
  const int nIter = K >> 7;

  const int csw0 = (fg * 16) ^ ((fr & 7) << 4);
  const int csw1 = (64 + fg * 16) ^ ((fr & 7) << 4);

  const int sc = (lane * 16) & 127;
  const size_t laneoff = (size_t)(lane >> 3) * K2 + (size_t)(sc ^ ((lane >> 3) << 4));
  const char* Asrc = (const char*)(A + (size_t)m0 * K) + laneoff;
  const char* Bsrc = (const char*)(Bt + (size_t)n0 * K) + laneoff;
  const int arow_wv = (wv >> 2) * 64 + (wv & 3) * 8;
  const int brow_wv = (wv >> 2) * 64 + (wv & 3) * 8;

  f32x4 acc[4][4];
  #pragma unroll
  for (int i = 0; i < 4; ++i)
    #pragma unroll
    for (int j = 0; j < 4; ++j) acc[i][j] = (f32x4){0.f, 0.f, 0.f, 0.f};

  auto stageA = [&](int b, int c, int kt) {
    GLDS16(Asrc + (size_t)(arow_wv + c * 32) * K2 + (size_t)kt * 128,
           lds + b * 49152 + c * 8192 + wv * 1024);
  };
  auto stageB = [&](int b, int j, int kt) {
    GLDS16(Bsrc + (size_t)((j & 1) * 128 + (j >> 1) * 32 + brow_wv) * K2 + (size_t)kt * 128,
           lds + b * 49152 + 16384 + j * 8192 + wv * 1024);
  };

  stageA(0, 0, 0); stageA(0, 1, 0);
  stageB(0, 0, 0); stageB(0, 1, 0); stageB(0, 2, 0); stageB(0, 3, 0);
  stageA(1, 0, 1); stageB(1, 0, 1); stageB(1, 1, 1);
  __builtin_amdgcn_sched_barrier(0);
  asm volatile("s_waitcnt vmcnt(3)" ::: "memory");
  __builtin_amdgcn_s_barrier();

  for (int i = 0; i < nIter; ++i) {
    const bool last = (i == nIter - 1);
    #pragma unroll
    for (int p = 0; p < 8; ++p) {
      const int b  = p >> 2;
      const int mh = (p >> 1) & 1;
      const int nh = p & 1;
      const char* Ab = lds + b * 49152;
      const char* Bb = Ab + 16384;
      __builtin_amdgcn_sched_barrier(0);
      short8 fa[2][2], fb[2][2];
      #pragma unroll
      for (int j = 0; j < 2; ++j) {
        const int row = mh * 64 + wm * 32 + j * 16 + fr;
        fa[j][0] = *(const short8*)(Ab + row * 128 + csw0);
        fa[j][1] = *(const short8*)(Ab + row * 128 + csw1);
      }
      #pragma unroll
      for (int n = 0; n < 2; ++n) {
        const int row = nh * 128 + (wn >> 1) * 64 + (wn & 1) * 32 + n * 16 + fr;
        fb[n][0] = *(const short8*)(Bb + row * 128 + csw0);
        fb[n][1] = *(const short8*)(Bb + row * 128 + csw1);
      }
      if (p == 0) stageA(1, 1, 2 * i + 1);
      if (p == 1) { stageB(1, 2, 2 * i + 1); stageB(1, 3, 2 * i + 1); }
      if (!last) {
        if (p == 2) stageA(0, 0, 2 * i + 2);
        if (p == 3) { stageB(0, 0, 2 * i + 2); stageB(0, 1, 2 * i + 2); }
        if (p == 4) stageA(0, 1, 2 * i + 2);
        if (p == 5) { stageB(0, 2, 2 * i + 2); stageB(0, 3, 2 * i + 2); }
        if (p == 6) stageA(1, 0, 2 * i + 3);
        if (p == 7) { stageB(1, 0, 2 * i + 3); stageB(1, 1, 2 * i + 3); }
      }
      __builtin_amdgcn_sched_barrier(0);
      __builtin_amdgcn_s_barrier();
      __builtin_amdgcn_sched_barrier(0);
      __builtin_amdgcn_s_setprio(1);
      #pragma unroll
      for (int j = 0; j < 2; ++j)
        #pragma unroll
        for (int n = 0; n < 2; ++n) {
          acc[mh * 2 + j][nh * 2 + n] = __builtin_amdgcn_mfma_f32_16x16x32_bf16(
              fa[j][0], fb[n][0], acc[mh * 2 + j][nh * 2 + n], 0, 0, 0);
          acc[mh * 2 + j][nh * 2 + n] = __builtin_amdgcn_mfma_f32_16x16x32_bf16(
              fa[j][1], fb[n][1], acc[mh * 2 + j][nh * 2 + n], 0, 0, 0);
        }
      __builtin_amdgcn_s_setprio(0);
      __builtin_amdgcn_sched_barrier(0);
      if (p == 3) {
        if (!last) asm volatile("s_waitcnt vmcnt(3)" ::: "memory");
        else       asm volatile("s_waitcnt vmcnt(0)" ::: "memory");
      }
      if (p == 7 && !last)
        asm volatile("s_waitcnt vmcnt(3)" ::: "memory");
      __builtin_amdgcn_s_barrier();
    }
  }

  // coalesced bf16 epilogue: per-wave [16][68] ushort region (8 x 2176B = 17408B)
  unsigned short* tw = (unsigned short*)(lds + wv * 2176);
  float bv4[4];
  #pragma unroll
  for (int ni = 0; ni < 4; ++ni)
    bv4[ni] = HAS_BIAS ? bias[n0 + wn * 64 + ni * 16 + fr] : 0.0f;
  #pragma unroll
  for (int mi = 0; mi < 4; ++mi) {
    #pragma unroll
    for (int ni = 0; ni < 4; ++ni)
      #pragma unroll
      for (int r = 0; r < 4; ++r) {
        float val = acc[mi][ni][r] + bv4[ni];
        if (GELU_ACT) val = 0.5f * val * (1.0f + erff(val * 0.70710678118f));
        tw[(fg * 4 + r) * 68 + ni * 16 + fr] = f2bf(val);
      }
    asm volatile("s_waitcnt lgkmcnt(0)" ::: "memory");
    __builtin_amdgcn_sched_barrier(0);
    #pragma unroll
    for (int rr = 0; rr < 4; ++rr) {
      const int row = rr * 4 + (lane >> 4);
      const int grow = m0 + wm * 64 + mi * 16 + row;
      const int gcol = n0 + wn * 64 + (lane & 15) * 4;
      ushort4 v = *(const ushort4*)&tw[row * 68 + (lane & 15) * 4];
      *(ushort4*)(out + (size_t)grow * N + gcol) = v;
    }
    asm volatile("s_waitcnt lgkmcnt(0)" ::: "memory");
    __builtin_amdgcn_sched_barrier(0);
  }
}

// ---------------- 256x256 8-phase bf16 GEMM (LM head), XCD-grouped, direct stores ----------------
__global__ __launch_bounds__(512, 1) void gemm8p_kernel(
    const unsigned short* __restrict__ A, const unsigned short* __restrict__ Bt,
    const float* __restrict__ bias, float* __restrict__ out, int M, int N, int K) {
  __shared__ __align__(16) char lds[131072];
  const int tid  = threadIdx.x;
  const int lane = tid & 63;
  const int wv   = tid >> 6;
  const int wm = wv >> 2, wn = wv & 3;

  const int mt = M >> 8;
  const int q8 = gridDim.x >> 3;
  const int g  = (blockIdx.x & 7) * q8 + (blockIdx.x >> 3);
  const int m0 = (g % mt) * 256, n0 = (g / mt) * 256;

  const int fr = lane & 15, fg = lane >> 4;
  const size_t K2 = (size_t)K * 2;
  const int nIter = K >> 7;

  const int csw0 = (fg * 16) ^ ((fr & 7) << 4);
  const int csw1 = (64 + fg * 16) ^ ((fr & 7) << 4);

  const int sc = (lane * 16) & 127;
  const size_t laneoff = (size_t)(lane >> 3) * K2 + (size_t)(sc ^ ((lane >> 3) << 4));
  const char* Asrc = (const char*)(A + (size_t)m0 * K) + (size_t)(wv * 8) * K2 + laneoff;
  const char* Bsrc = (const char*)(Bt + (size_t)n0 * K) + laneoff;

  f32x4 acc[8][4];
  #pragma unroll
  for (int i = 0; i < 8; ++i)
    #pragma unroll
    for (int j = 0; j < 4; ++j) acc[i][j] = (f32x4){0.f, 0.f, 0.f, 0.f};

  auto stageA = [&](int b, int q, int kt) {
    GLDS16(Asrc + (size_t)(q * 64) * K2 + (size_t)kt * 128,
           lds + b * 65536 + q * 8192 + wv * 1024);
  };
  auto stageB = [&](int b, int j, int o, int kt) {
    const int gw = j * 64 + wv * 8;
    const int rw = ((gw >> 5) << 6) + (gw & 31) + o * 32;
    GLDS16(Bsrc + (size_t)rw * K2 + (size_t)kt * 128,
           lds + b * 65536 + 32768 + rw * 128);
  };

  stageA(0, 0, 0); stageA(0, 2, 0);
  stageB(0, 0, 0, 0); stageB(0, 1, 0, 0);
  stageA(0, 1, 0); stageA(0, 3, 0);
  stageB(0, 0, 1, 0); stageB(0, 1, 1, 0);
  stageA(1, 0, 1); stageA(1, 2, 1);
  stageB(1, 0, 0, 1); stageB(1, 1, 0, 1);
  __builtin_amdgcn_sched_barrier(0);
  asm volatile("s_waitcnt vmcnt(4)" ::: "memory");
  __builtin_amdgcn_s_barrier();

  for (int i = 0; i < nIter; ++i) {
    const bool last = (i == nIter - 1);
    #pragma unroll
    for (int p = 0; p < 8; ++p) {
      const int b  = p >> 2;
      const int mh = (p & 3) >> 1;
      const int nh = p & 1;
      const char* Ab = lds + b * 65536;
      const char* Bb = Ab + 32768;
      __builtin_amdgcn_sched_barrier(0);
      short8 fa[4][2], fb[2][2];
      #pragma unroll
      for (int j = 0; j < 4; ++j) {
        const int row = wm * 128 + mh * 64 + j * 16 + fr;
        fa[j][0] = *(const short8*)(Ab + row * 128 + csw0);
        fa[j][1] = *(const short8*)(Ab + row * 128 + csw1);
      }
      #pragma unroll
      for (int n = 0; n < 2; ++n) {
        const int row = wn * 64 + nh * 32 + n * 16 + fr;
        fb[n][0] = *(const short8*)(Bb + row * 128 + csw0);
        fb[n][1] = *(const short8*)(Bb + row * 128 + csw1);
      }
      if (p == 0) { stageA(1, 1, 2 * i + 1); stageA(1, 3, 2 * i + 1); }
      if (p == 1) { stageB(1, 0, 1, 2 * i + 1); stageB(1, 1, 1, 2 * i + 1); }
      if (!last) {
        if (p == 2) { stageA(0, 0, 2 * i + 2); stageA(0, 2, 2 * i + 2); }
        if (p == 3) { stageB(0, 0, 0, 2 * i + 2); stageB(0, 1, 0, 2 * i + 2); }
        if (p == 4) { stageA(0, 1, 2 * i + 2); stageA(0, 3, 2 * i + 2); }
        if (p == 5) { stageB(0, 0, 1, 2 * i + 2); stageB(0, 1, 1, 2 * i + 2); }
        if (p == 6) { stageA(1, 0, 2 * i + 3); stageA(1, 2, 2 * i + 3); }
        if (p == 7) { stageB(1, 0, 0, 2 * i + 3); stageB(1, 1, 0, 2 * i + 3); }
      }
      __builtin_amdgcn_sched_barrier(0);
      __builtin_amdgcn_s_barrier();
      __builtin_amdgcn_sched_barrier(0);
      __builtin_amdgcn_s_setprio(1);
      #pragma unroll
      for (int j = 0; j < 4; ++j)
        #pragma unroll
        for (int n = 0; n < 2; ++n) {
          acc[mh * 4 + j][nh * 2 + n] = __builtin_amdgcn_mfma_f32_16x16x32_bf16(
              fa[j][0], fb[n][0], acc[mh * 4 + j][nh * 2 + n], 0, 0, 0);
          acc[mh * 4 + j][nh * 2 + n] = __builtin_amdgcn_mfma_f32_16x16x32_bf16(
              fa[j][1], fb[n][1], acc[mh * 4 + j][nh * 2 + n], 0, 0, 0);
        }
      __builtin_amdgcn_s_setprio(0);
      __builtin_amdgcn_sched_barrier(0);
      if (p == 3) {
        if (!last) asm volatile("s_waitcnt vmcnt(4)" ::: "memory");
        else       asm volatile("s_waitcnt vmcnt(0)" ::: "memory");
      }
      if (p == 7 && !last)
        asm volatile("s_waitcnt vmcnt(4)" ::: "memory");
      __builtin_amdgcn_s_barrier();
    }
  }

  #pragma unroll
  for (int mi = 0; mi < 8; ++mi) {
    #pragma unroll
    for (int ni = 0; ni < 4; ++ni) {
      const int col = n0 + wn * 64 + ni * 16 + fr;
      const float bv = bias[col];
      #pragma unroll
      for (int r = 0; r < 4; ++r) {
        const int row = m0 + wm * 128 + mi * 16 + fg * 4 + r;
        out[(size_t)row * N + col] = acc[mi][ni][r] + bv;
      }
    }
  }
}

extern "C" void kernel_launch(void* const* d_in, const int* in_sizes, int n_in,
                              void* d_out, int out_size, void* d_ws, size_t ws_size,
                              hipStream_t stream) {
  const int*   idx   = (const int*)  d_in[0];
  const float* tok_w = (const float*)d_in[1];
  const float* pos_w = (const float*)d_in[2];
  const float* ln1_g = (const float*)d_in[3];
  const float* ln1_b = (const float*)d_in[4];
  const float* wq    = (const float*)d_in[5];
  const float* wk    = (const float*)d_in[6];
  const float* wv    = (const float*)d_in[7];
  const float* wp    = (const float*)d_in[8];
  const float* bp    = (const float*)d_in[9];
  const float* ln2_g = (const float*)d_in[10];
  const float* ln2_b = (const float*)d_in[11];
  const float* w1    = (const float*)d_in[12];
  const float* b1    = (const float*)d_in[13];
  const float* w2    = (const float*)d_in[14];
  const float* b2    = (const float*)d_in[15];
  const float* lnf_g = (const float*)d_in[16];
  const float* lnf_b = (const float*)d_in[17];
  const float* wlm   = (const float*)d_in[18];
  const float* blm   = (const float*)d_in[19];

  const int M = B_BATCH * T_SEQ;  // 2048
  const size_t EE = (size_t)E_DIM * E_DIM;
  const size_t EF = (size_t)E_DIM * F_DIM;
  char* p = (char*)d_ws;
  float* x            = (float*)p;          p += (size_t)M * E_DIM * 4;
  unsigned short* hb  = (unsigned short*)p; p += (size_t)M * E_DIM * 2;
  unsigned short* qkb = (unsigned short*)p; p += (size_t)M * 2 * E_DIM * 2;
  unsigned short* vtb = (unsigned short*)p; p += (size_t)M * E_DIM * 2;
  unsigned short* yb  = (unsigned short*)p; p += (size_t)M * E_DIM * 2;
  unsigned short* tb  = (unsigned short*)p; p += (size_t)M * F_DIM * 2;
  unsigned short* wtb = (unsigned short*)p; p += (size_t)V_VOCAB * E_DIM * 2;

  embed_kernel<<<M * E_DIM / 4 / 256, 256, 0, stream>>>(idx, tok_w, pos_w, x);

  for (int l = 0; l < L_LAYERS; ++l) {
    wtrans6ln_kernel<<<5120, 256, 0, stream>>>(
        wq + l * EE, wk + l * EE, wv + l * EE, wp + l * EE,
        w1 + l * EF, w2 + l * EF,
        ln1_g + (size_t)l * E_DIM, ln1_b + (size_t)l * E_DIM, x, wtb, hb);
    gemm_bt_kernel<2, false, false, false>
        <<<(M / 64) * (3 * E_DIM / 64), 256, 0, stream>>>(
        hb, wtb, nullptr, nullptr, qkb, vtb, M, 3 * E_DIM, E_DIM);
    attn_mfma_kernel<<<dim3(16, B_BATCH * H_HEADS), 512, 0, stream>>>(qkb, vtb, yb);
    gemm_bt_kernel<0, true, false, true>
        <<<(M / 64) * (E_DIM / 64), 256, 0, stream>>>(
        yb, wtb + 3 * EE, bp + (size_t)l * E_DIM, x, x, nullptr, M, E_DIM, E_DIM);
    ln_kernel<<<M, 256, 0, stream>>>(x, ln2_g + (size_t)l * E_DIM, ln2_b + (size_t)l * E_DIM, hb);
    gemm8p2_kernel<true, true>
        <<<(M / 128) * (F_DIM / 256), 512, 0, stream>>>(
        hb, wtb + 4 * EE, b1 + (size_t)l * F_DIM, tb, M, F_DIM, E_DIM);
    gemm_bt_kernel<0, true, false, true>
        <<<(M / 64) * (E_DIM / 64), 256, 0, stream>>>(
        tb, wtb + 4 * EE + EF, b2 + (size_t)l * E_DIM, x, x, nullptr, M, E_DIM, F_DIM);
  }
  wtransv_ln_kernel<<<10048, 256, 0, stream>>>(wlm, lnf_g, lnf_b, x, wtb, hb);
  gemm8p_kernel<<<(M / 256) * (V_VOCAB / 256), 512, 0, stream>>>(
      hb, wtb, blm, (float*)d_out, M, V_VOCAB, E_DIM);
}